// Round 1
// baseline (1182.189 us; speedup 1.0000x reference)
//
#include <hip/hip_runtime.h>
#include <cstdint>

#define NN 50000
#define HIDD 64
#define NBLK 12500              // NN/4 nodes per 256-thread block (4 waves)
#define EPSV 1e-5f

// ---------------- CSR build ----------------

__global__ void k_hist(const int* __restrict__ dst, int E, int* __restrict__ deg) {
    int e = blockIdx.x * blockDim.x + threadIdx.x;
    if (e < E) atomicAdd(&deg[dst[e]], 1);
}

// single-block exclusive scan over deg[0..N) -> rowstart[0..N], pos copy
__global__ void k_scan(const int* __restrict__ deg, int* __restrict__ rowstart,
                       int* __restrict__ pos, int N) {
    __shared__ int lds[1024];
    int t = threadIdx.x;
    int chunk = (N + 1023) / 1024;
    int lo = t * chunk, hi = min(lo + chunk, N);
    int s = 0;
    for (int i = lo; i < hi; ++i) s += deg[i];
    lds[t] = s;
    __syncthreads();
    for (int off = 1; off < 1024; off <<= 1) {
        int v = (t >= off) ? lds[t - off] : 0;
        __syncthreads();
        lds[t] += v;
        __syncthreads();
    }
    int run = (t == 0) ? 0 : lds[t - 1];
    for (int i = lo; i < hi; ++i) {
        rowstart[i] = run;
        pos[i] = run;
        run += deg[i];
    }
    if (lo < N && hi == N) rowstart[N] = run;   // total = E
}

__global__ void k_scatter(const int* __restrict__ src, const int* __restrict__ dst, int E,
                          int* __restrict__ pos, int* __restrict__ colsrc) {
    int e = blockIdx.x * blockDim.x + threadIdx.x;
    if (e < E) {
        int d = dst[e];
        int p = atomicAdd(&pos[d], 1);
        colsrc[p] = src[e];
    }
}

// ---------------- per-layer: node -> (q_s, q_d) ----------------
// q_s[v][c] = sum_k p[v][k] * W1[k][c]
// q_d[v][c] = sum_k p[v][k] * (W1[3+k][c] - W1[k][c]) + b1[c]
// BN+relu of the previous layer is fused here (scale/shift per pos-col).
__global__ __launch_bounds__(256) void k_q(
    const float* __restrict__ pin, int pstride, int c0, int c1, int c2,
    const float* __restrict__ W1l, const float* __restrict__ b1l,
    const float* __restrict__ scale, const float* __restrict__ shift, int use_bn,
    float* __restrict__ qs, float* __restrict__ qd) {
    int idx = blockIdx.x * 256 + threadIdx.x;   // v*64 + c
    int v = idx >> 6, c = idx & 63;
    const float* prow = pin + (size_t)v * pstride;
    float p0 = prow[c0], p1 = prow[c1], p2 = prow[c2];
    if (use_bn) {
        p0 = fmaxf(0.f, p0 * scale[0] + shift[0]);
        p1 = fmaxf(0.f, p1 * scale[1] + shift[1]);
        p2 = fmaxf(0.f, p2 * scale[2] + shift[2]);
    }
    float w0 = W1l[0 * 64 + c], w1 = W1l[1 * 64 + c], w2 = W1l[2 * 64 + c];
    float w3 = W1l[3 * 64 + c], w4 = W1l[4 * 64 + c], w5 = W1l[5 * 64 + c];
    qs[idx] = p0 * w0 + p1 * w1 + p2 * w2;
    qd[idx] = p0 * (w3 - w0) + p1 * (w4 - w1) + p2 * (w5 - w2) + b1l[c];
}

// ---------------- gather + reduce, layers 0..4 (3 output cols) ----------------
__global__ __launch_bounds__(256) void k_gather3(
    const float* __restrict__ qs, const float* __restrict__ qd,
    const int* __restrict__ rowstart, const int* __restrict__ colsrc,
    const float* __restrict__ W2l, const float* __restrict__ b2l,
    float* __restrict__ pnext, float* __restrict__ partials) {
    int tid = threadIdx.x;
    int w = tid >> 6, lane = tid & 63;
    int v = blockIdx.x * 4 + w;
    float qdv = qd[v * 64 + lane];
    float acc = fmaxf(0.f, qs[v * 64 + lane] + qdv);   // self loop
    int start = rowstart[v], end = rowstart[v + 1];
    int i = start;
    while (i < end) {
        int cnt = min(64, end - i);
        int sl = (lane < cnt) ? colsrc[i + lane] : 0;
        for (int j = 0; j < cnt; ++j) {
            int s = __shfl(sl, j);
            acc += fmaxf(0.f, qs[s * 64 + lane] + qdv);
        }
        i += cnt;
    }
    float degp1 = (float)(end - start + 1);
    __shared__ float part[4][8];
    const int cols[3] = {0, 1, 14};
#pragma unroll
    for (int j = 0; j < 3; ++j) {
        float t = acc * W2l[lane * 64 + cols[j]];
        for (int off = 32; off; off >>= 1) t += __shfl_xor(t, off);
        if (lane == 0) {
            float val = t + degp1 * b2l[cols[j]];
            pnext[v * 3 + j] = val;
            part[w][j] = val;
            part[w][3 + j] = val * val;
        }
    }
    __syncthreads();
    if (tid < 6) {
        float s = part[0][tid] + part[1][tid] + part[2][tid] + part[3][tid];
        partials[blockIdx.x * 8 + tid] = s;
    }
}

// ---------------- BN finalize (3 cols): partials -> scale/shift ----------------
__global__ void k_bnfin(const float* __restrict__ partials, int nb,
                        const float* __restrict__ gamma_l, const float* __restrict__ beta_l,
                        float* __restrict__ scale, float* __restrict__ shift) {
    __shared__ float lds[256][6];
    int t = threadIdx.x;
    float s[6] = {0, 0, 0, 0, 0, 0};
    for (int b = t; b < nb; b += 256)
        for (int j = 0; j < 6; ++j) s[j] += partials[b * 8 + j];
    for (int j = 0; j < 6; ++j) lds[t][j] = s[j];
    __syncthreads();
    for (int off = 128; off; off >>= 1) {
        if (t < off)
            for (int j = 0; j < 6; ++j) lds[t][j] += lds[t + off][j];
        __syncthreads();
    }
    if (t < 3) {
        const int cols[3] = {0, 1, 14};
        float mu = lds[0][t] / (float)NN;
        float var = lds[0][t + 3] / (float)NN - mu * mu;
        float rs = rsqrtf(var + EPSV);
        float g = gamma_l[cols[t]];
        scale[t] = rs * g;
        shift[t] = beta_l[cols[t]] - mu * rs * g;
    }
}

// ---------------- gather + full 64-col matmul, layer 5 ----------------
__global__ __launch_bounds__(256) void k_gather_full(
    const float* __restrict__ qs, const float* __restrict__ qd,
    const int* __restrict__ rowstart, const int* __restrict__ colsrc,
    const float* __restrict__ W2l, const float* __restrict__ b2l,
    float* __restrict__ out) {
    int tid = threadIdx.x;
    int w = tid >> 6, lane = tid & 63;
    int v = blockIdx.x * 4 + w;
    float qdv = qd[v * 64 + lane];
    float acc = fmaxf(0.f, qs[v * 64 + lane] + qdv);   // self loop
    int start = rowstart[v], end = rowstart[v + 1];
    int i = start;
    while (i < end) {
        int cnt = min(64, end - i);
        int sl = (lane < cnt) ? colsrc[i + lane] : 0;
        for (int j = 0; j < cnt; ++j) {
            int s = __shfl(sl, j);
            acc += fmaxf(0.f, qs[s * 64 + lane] + qdv);
        }
        i += cnt;
    }
    __shared__ float lds[4][64];
    lds[w][lane] = acc;
    __syncthreads();
    float degp1 = (float)(end - start + 1);
    float sum = degp1 * b2l[lane];
    for (int k = 0; k < 64; ++k) sum += lds[w][k] * W2l[k * 64 + lane];
    out[v * 64 + lane] = sum;
}

// ---------------- launch ----------------

static inline size_t align_up(size_t x) { return (x + 255) & ~(size_t)255; }

extern "C" void kernel_launch(void* const* d_in, const int* in_sizes, int n_in,
                              void* d_out, int out_size, void* d_ws, size_t ws_size,
                              hipStream_t stream) {
    const float* x     = (const float*)d_in[0];
    const int*   ei    = (const int*)d_in[1];
    const float* W1    = (const float*)d_in[2];
    const float* b1    = (const float*)d_in[3];
    const float* W2    = (const float*)d_in[4];
    const float* b2    = (const float*)d_in[5];
    const float* gamma = (const float*)d_in[6];
    const float* beta  = (const float*)d_in[7];
    float* out = (float*)d_out;
    const int E = in_sizes[1] / 2;           // 1,600,000
    const int* src = ei;
    const int* dst = ei + E;

    // workspace carve
    char* base = (char*)d_ws;
    size_t off = 0;
    float* qs = (float*)(base + off);       off = align_up(off + (size_t)NN * 64 * 4);
    float* qd = (float*)(base + off);       off = align_up(off + (size_t)NN * 64 * 4);
    float* pA = (float*)(base + off);       off = align_up(off + (size_t)NN * 3 * 4);
    float* pB = (float*)(base + off);       off = align_up(off + (size_t)NN * 3 * 4);
    int* deg      = (int*)(base + off);     off = align_up(off + (size_t)NN * 4);
    int* rowstart = (int*)(base + off);     off = align_up(off + (size_t)(NN + 1) * 4);
    int* pos      = (int*)(base + off);     off = align_up(off + (size_t)NN * 4);
    int* colsrc   = (int*)(base + off);     off = align_up(off + (size_t)E * 4);
    float* partials = (float*)(base + off); off = align_up(off + (size_t)NBLK * 8 * 4);
    float* scale = (float*)(base + off);    off = align_up(off + 64 * 4);
    float* shift = (float*)(base + off);    off = align_up(off + 64 * 4);
    (void)ws_size; (void)n_in; (void)out_size;

    // CSR build (once per call; reused by all 6 layers)
    hipMemsetAsync(deg, 0, (size_t)NN * 4, stream);
    k_hist<<<(E + 255) / 256, 256, 0, stream>>>(dst, E, deg);
    k_scan<<<1, 1024, 0, stream>>>(deg, rowstart, pos, NN);
    k_scatter<<<(E + 255) / 256, 256, 0, stream>>>(src, dst, E, pos, colsrc);

    float* pc = pA;
    float* pn = pB;
    for (int l = 0; l < 6; ++l) {
        const float* pin = (l == 0) ? x : pc;
        int pstride = (l == 0) ? 16 : 3;
        int c0 = 0, c1 = 1, c2 = (l == 0) ? 14 : 2;
        k_q<<<NBLK, 256, 0, stream>>>(pin, pstride, c0, c1, c2,
                                      W1 + (size_t)l * 6 * 64, b1 + (size_t)l * 64,
                                      scale, shift, (l > 0) ? 1 : 0, qs, qd);
        if (l < 5) {
            k_gather3<<<NBLK, 256, 0, stream>>>(qs, qd, rowstart, colsrc,
                                                W2 + (size_t)l * 64 * 64, b2 + (size_t)l * 64,
                                                pn, partials);
            k_bnfin<<<1, 256, 0, stream>>>(partials, NBLK,
                                           gamma + (size_t)l * 64, beta + (size_t)l * 64,
                                           scale, shift);
            float* tmp = pc; pc = pn; pn = tmp;
        } else {
            k_gather_full<<<NBLK, 256, 0, stream>>>(qs, qd, rowstart, colsrc,
                                                    W2 + (size_t)5 * 64 * 64, b2 + (size_t)5 * 64,
                                                    out);
        }
    }
}

// Round 2
// 745.672 us; speedup vs baseline: 1.5854x; 1.5854x over previous
//
#include <hip/hip_runtime.h>
#include <hip/hip_fp16.h>
#include <cstdint>

#define NN 50000
#define NBLK 12500              // NN/4 nodes per 256-thread block (4 waves)
#define NSB 196                 // scan blocks: 196*256 = 50176 >= NN
#define EPSV 1e-5f

// ---------------- CSR build ----------------

__global__ void k_hist(const int* __restrict__ dst, int E, int* __restrict__ deg) {
    int e = blockIdx.x * blockDim.x + threadIdx.x;
    if (e < E) atomicAdd(&deg[dst[e]], 1);
}

// hierarchical exclusive scan: A) per-block inclusive scan, B) scan block sums,
// C) combine -> rowstart/pos (all coalesced)
__global__ __launch_bounds__(256) void k_scanA(const int* __restrict__ deg, int N,
                                               int* __restrict__ presum, int* __restrict__ blocksum) {
    __shared__ int lds[256];
    int t = threadIdx.x, g = blockIdx.x * 256 + t;
    int v = (g < N) ? deg[g] : 0;
    lds[t] = v;
    __syncthreads();
    for (int off = 1; off < 256; off <<= 1) {
        int x = (t >= off) ? lds[t - off] : 0;
        __syncthreads();
        lds[t] += x;
        __syncthreads();
    }
    if (g < N) presum[g] = lds[t];               // block-local inclusive
    if (t == 255) blocksum[blockIdx.x] = lds[255];
}

__global__ __launch_bounds__(256) void k_scanB(const int* __restrict__ blocksum,
                                               int nb, int* __restrict__ blockoff) {
    __shared__ int lds[256];
    int t = threadIdx.x;
    int v = (t < nb) ? blocksum[t] : 0;
    lds[t] = v;
    __syncthreads();
    for (int off = 1; off < 256; off <<= 1) {
        int x = (t >= off) ? lds[t - off] : 0;
        __syncthreads();
        lds[t] += x;
        __syncthreads();
    }
    if (t < nb) blockoff[t] = lds[t] - v;        // exclusive
}

__global__ __launch_bounds__(256) void k_scanC(const int* __restrict__ presum,
                                               const int* __restrict__ deg,
                                               const int* __restrict__ blockoff,
                                               int N, int E,
                                               int* __restrict__ rowstart, int* __restrict__ pos) {
    int g = blockIdx.x * 256 + threadIdx.x;
    if (g < N) {
        int r = presum[g] - deg[g] + blockoff[blockIdx.x];
        rowstart[g] = r;
        pos[g] = r;
    }
    if (g == N) rowstart[N] = E;
}

__global__ void k_scatter(const int* __restrict__ src, const int* __restrict__ dst, int E,
                          int* __restrict__ pos, int* __restrict__ colsrc) {
    int e = blockIdx.x * blockDim.x + threadIdx.x;
    if (e < E) {
        int d = dst[e];
        int p = atomicAdd(&pos[d], 1);
        colsrc[p] = src[e];
    }
}

// ---------------- per-layer: node -> (q_s, q_d) in fp16 ----------------
__global__ __launch_bounds__(256) void k_q(
    const float* __restrict__ pin, int pstride, int c0, int c1, int c2,
    const float* __restrict__ W1l, const float* __restrict__ b1l,
    const float* __restrict__ scale, const float* __restrict__ shift, int use_bn,
    __half* __restrict__ qs, __half* __restrict__ qd) {
    int idx = blockIdx.x * 256 + threadIdx.x;   // v*64 + c
    int v = idx >> 6, c = idx & 63;
    const float* prow = pin + (size_t)v * pstride;
    float p0 = prow[c0], p1 = prow[c1], p2 = prow[c2];
    if (use_bn) {
        p0 = fmaxf(0.f, p0 * scale[0] + shift[0]);
        p1 = fmaxf(0.f, p1 * scale[1] + shift[1]);
        p2 = fmaxf(0.f, p2 * scale[2] + shift[2]);
    }
    float w0 = W1l[0 * 64 + c], w1 = W1l[1 * 64 + c], w2 = W1l[2 * 64 + c];
    float w3 = W1l[3 * 64 + c], w4 = W1l[4 * 64 + c], w5 = W1l[5 * 64 + c];
    qs[idx] = __float2half(p0 * w0 + p1 * w1 + p2 * w2);
    qd[idx] = __float2half(p0 * (w3 - w0) + p1 * (w4 - w1) + p2 * (w5 - w2) + b1l[c]);
}

// edge accumulation core: acc = sum over incoming edges of relu(qs[src]+qd[v])
__device__ __forceinline__ float edge_accum(
    const __half* __restrict__ qs, float qdv, int lane,
    const int* __restrict__ colsrc, int start, int end) {
    float acc = 0.f;
    int i = start;
    while (i < end) {
        int cnt = min(64, end - i);
        int sl = (lane < cnt) ? colsrc[i + lane] : 0;
        int j = 0;
        for (; j + 4 <= cnt; j += 4) {
            int s0 = __shfl(sl, j), s1 = __shfl(sl, j + 1);
            int s2 = __shfl(sl, j + 2), s3 = __shfl(sl, j + 3);
            float f0 = __half2float(qs[(size_t)s0 * 64 + lane]);
            float f1 = __half2float(qs[(size_t)s1 * 64 + lane]);
            float f2 = __half2float(qs[(size_t)s2 * 64 + lane]);
            float f3 = __half2float(qs[(size_t)s3 * 64 + lane]);
            acc += fmaxf(0.f, f0 + qdv);
            acc += fmaxf(0.f, f1 + qdv);
            acc += fmaxf(0.f, f2 + qdv);
            acc += fmaxf(0.f, f3 + qdv);
        }
        for (; j < cnt; ++j) {
            int s = __shfl(sl, j);
            acc += fmaxf(0.f, __half2float(qs[(size_t)s * 64 + lane]) + qdv);
        }
        i += cnt;
    }
    return acc;
}

// ---------------- gather + reduce, layers 0..4 (3 output cols) ----------------
__global__ __launch_bounds__(256) void k_gather3(
    const __half* __restrict__ qs, const __half* __restrict__ qd,
    const int* __restrict__ rowstart, const int* __restrict__ colsrc,
    const float* __restrict__ W2l, const float* __restrict__ b2l,
    float* __restrict__ pnext, float* __restrict__ partials) {
    int tid = threadIdx.x;
    int w = tid >> 6, lane = tid & 63;
    int v = blockIdx.x * 4 + w;
    float qdv = __half2float(qd[v * 64 + lane]);
    int start = rowstart[v], end = rowstart[v + 1];
    float acc = fmaxf(0.f, __half2float(qs[v * 64 + lane]) + qdv);   // self loop
    acc += edge_accum(qs, qdv, lane, colsrc, start, end);
    float degp1 = (float)(end - start + 1);
    __shared__ float part[4][8];
    const int cols[3] = {0, 1, 14};
#pragma unroll
    for (int j = 0; j < 3; ++j) {
        float t = acc * W2l[lane * 64 + cols[j]];
        for (int off = 32; off; off >>= 1) t += __shfl_xor(t, off);
        if (lane == 0) {
            float val = t + degp1 * b2l[cols[j]];
            pnext[v * 3 + j] = val;
            part[w][j] = val;
            part[w][3 + j] = val * val;
        }
    }
    __syncthreads();
    if (tid < 6) {
        float s = part[0][tid] + part[1][tid] + part[2][tid] + part[3][tid];
        partials[blockIdx.x * 8 + tid] = s;
    }
}

// ---------------- BN finalize (3 cols): partials -> scale/shift ----------------
__global__ void k_bnfin(const float* __restrict__ partials, int nb,
                        const float* __restrict__ gamma_l, const float* __restrict__ beta_l,
                        float* __restrict__ scale, float* __restrict__ shift) {
    __shared__ float lds[256][6];
    int t = threadIdx.x;
    float s[6] = {0, 0, 0, 0, 0, 0};
    for (int b = t; b < nb; b += 256)
        for (int j = 0; j < 6; ++j) s[j] += partials[b * 8 + j];
    for (int j = 0; j < 6; ++j) lds[t][j] = s[j];
    __syncthreads();
    for (int off = 128; off; off >>= 1) {
        if (t < off)
            for (int j = 0; j < 6; ++j) lds[t][j] += lds[t + off][j];
        __syncthreads();
    }
    if (t < 3) {
        const int cols[3] = {0, 1, 14};
        float mu = lds[0][t] / (float)NN;
        float var = lds[0][t + 3] / (float)NN - mu * mu;
        float rs = rsqrtf(var + EPSV);
        float g = gamma_l[cols[t]];
        scale[t] = rs * g;
        shift[t] = beta_l[cols[t]] - mu * rs * g;
    }
}

// ---------------- gather + full 64-col matmul, layer 5 ----------------
__global__ __launch_bounds__(256) void k_gather_full(
    const __half* __restrict__ qs, const __half* __restrict__ qd,
    const int* __restrict__ rowstart, const int* __restrict__ colsrc,
    const float* __restrict__ W2l, const float* __restrict__ b2l,
    float* __restrict__ out) {
    int tid = threadIdx.x;
    int w = tid >> 6, lane = tid & 63;
    int v = blockIdx.x * 4 + w;
    float qdv = __half2float(qd[v * 64 + lane]);
    int start = rowstart[v], end = rowstart[v + 1];
    float acc = fmaxf(0.f, __half2float(qs[v * 64 + lane]) + qdv);   // self loop
    acc += edge_accum(qs, qdv, lane, colsrc, start, end);
    __shared__ float lds[4][64];
    lds[w][lane] = acc;
    __syncthreads();
    float degp1 = (float)(end - start + 1);
    float sum = degp1 * b2l[lane];
    for (int k = 0; k < 64; ++k) sum += lds[w][k] * W2l[k * 64 + lane];
    out[v * 64 + lane] = sum;
}

// ---------------- launch ----------------

static inline size_t align_up(size_t x) { return (x + 255) & ~(size_t)255; }

extern "C" void kernel_launch(void* const* d_in, const int* in_sizes, int n_in,
                              void* d_out, int out_size, void* d_ws, size_t ws_size,
                              hipStream_t stream) {
    const float* x     = (const float*)d_in[0];
    const int*   ei    = (const int*)d_in[1];
    const float* W1    = (const float*)d_in[2];
    const float* b1    = (const float*)d_in[3];
    const float* W2    = (const float*)d_in[4];
    const float* b2    = (const float*)d_in[5];
    const float* gamma = (const float*)d_in[6];
    const float* beta  = (const float*)d_in[7];
    float* out = (float*)d_out;
    const int E = in_sizes[1] / 2;           // 1,600,000
    const int* src = ei;
    const int* dst = ei + E;

    // workspace carve
    char* base = (char*)d_ws;
    size_t off = 0;
    __half* qs = (__half*)(base + off);     off = align_up(off + (size_t)NN * 64 * 2);
    __half* qd = (__half*)(base + off);     off = align_up(off + (size_t)NN * 64 * 2);
    float* pA = (float*)(base + off);       off = align_up(off + (size_t)NN * 3 * 4);
    float* pB = (float*)(base + off);       off = align_up(off + (size_t)NN * 3 * 4);
    int* deg      = (int*)(base + off);     off = align_up(off + (size_t)NN * 4);
    int* rowstart = (int*)(base + off);     off = align_up(off + (size_t)(NN + 1) * 4);
    int* pos      = (int*)(base + off);     off = align_up(off + (size_t)NN * 4);
    int* colsrc   = (int*)(base + off);     off = align_up(off + (size_t)E * 4);
    int* presum   = (int*)(base + off);     off = align_up(off + (size_t)NSB * 256 * 4);
    int* blocksum = (int*)(base + off);     off = align_up(off + (size_t)NSB * 4);
    int* blockoff = (int*)(base + off);     off = align_up(off + (size_t)NSB * 4);
    float* partials = (float*)(base + off); off = align_up(off + (size_t)NBLK * 8 * 4);
    float* scale = (float*)(base + off);    off = align_up(off + 64 * 4);
    float* shift = (float*)(base + off);    off = align_up(off + 64 * 4);
    (void)ws_size; (void)n_in; (void)out_size;

    // CSR build (once per call; reused by all 6 layers)
    hipMemsetAsync(deg, 0, (size_t)NN * 4, stream);
    k_hist<<<(E + 255) / 256, 256, 0, stream>>>(dst, E, deg);
    k_scanA<<<NSB, 256, 0, stream>>>(deg, NN, presum, blocksum);
    k_scanB<<<1, 256, 0, stream>>>(blocksum, NSB, blockoff);
    k_scanC<<<NSB, 256, 0, stream>>>(presum, deg, blockoff, NN, E, rowstart, pos);
    k_scatter<<<(E + 255) / 256, 256, 0, stream>>>(src, dst, E, pos, colsrc);

    float* pc = pA;
    float* pn = pB;
    for (int l = 0; l < 6; ++l) {
        const float* pin = (l == 0) ? x : pc;
        int pstride = (l == 0) ? 16 : 3;
        int c0 = 0, c1 = 1, c2 = (l == 0) ? 14 : 2;
        k_q<<<NBLK, 256, 0, stream>>>(pin, pstride, c0, c1, c2,
                                      W1 + (size_t)l * 6 * 64, b1 + (size_t)l * 64,
                                      scale, shift, (l > 0) ? 1 : 0, qs, qd);
        if (l < 5) {
            k_gather3<<<NBLK, 256, 0, stream>>>(qs, qd, rowstart, colsrc,
                                                W2 + (size_t)l * 64 * 64, b2 + (size_t)l * 64,
                                                pn, partials);
            k_bnfin<<<1, 256, 0, stream>>>(partials, NBLK,
                                           gamma + (size_t)l * 64, beta + (size_t)l * 64,
                                           scale, shift);
            float* tmp = pc; pc = pn; pn = tmp;
        } else {
            k_gather_full<<<NBLK, 256, 0, stream>>>(qs, qd, rowstart, colsrc,
                                                    W2 + (size_t)5 * 64 * 64, b2 + (size_t)5 * 64,
                                                    out);
        }
    }
}

// Round 3
// 574.173 us; speedup vs baseline: 2.0589x; 1.2987x over previous
//
#include <hip/hip_runtime.h>
#include <hip/hip_fp16.h>
#include <cstdint>

#define NN 50000
#define NBLK 12500              // NN/4 nodes per 256-thread block (4 waves)
#define EPSV 1e-5f

// bucket sort params
#define NPB 128                 // nodes per bucket
#define BSH 7                   // log2(NPB)
#define NBKT 391                // ceil(NN/NPB)
#define CHUNK 4096              // edges per stage-1 block
#define EPT 16                  // edges per thread (CHUNK/256)
#define LDSE 6144               // per-bucket LDS edge capacity (mean ~4096, 32 sigma)

// ---------------- stage 1: per-chunk bucket histogram ----------------
__global__ __launch_bounds__(256) void k_hist1(const int* __restrict__ dst, int E, int nchunk,
                                               int* __restrict__ hist) {
    __shared__ int cnt[NBKT];
    int t = threadIdx.x, blk = blockIdx.x;
    for (int b = t; b < NBKT; b += 256) cnt[b] = 0;
    __syncthreads();
    int base = blk * CHUNK;
#pragma unroll
    for (int k = 0; k < EPT; ++k) {
        int e = base + k * 256 + t;
        if (e < E) atomicAdd(&cnt[dst[e] >> BSH], 1);
    }
    __syncthreads();
    for (int b = t; b < NBKT; b += 256) hist[(size_t)b * nchunk + blk] = cnt[b];
}

// ---------------- generic hierarchical exclusive scan ----------------
__global__ __launch_bounds__(256) void k_scanA(const int* __restrict__ in, int n,
                                               int* __restrict__ presum, int* __restrict__ blocksum) {
    __shared__ int lds[256];
    int t = threadIdx.x, g = blockIdx.x * 256 + t;
    int v = (g < n) ? in[g] : 0;
    lds[t] = v;
    __syncthreads();
    for (int off = 1; off < 256; off <<= 1) {
        int x = (t >= off) ? lds[t - off] : 0;
        __syncthreads();
        lds[t] += x;
        __syncthreads();
    }
    if (g < n) presum[g] = lds[t];               // block-local inclusive
    if (t == 255) blocksum[blockIdx.x] = lds[255];
}

// single-block loop-carried exclusive scan of nb block sums
__global__ __launch_bounds__(256) void k_scanB(const int* __restrict__ blocksum,
                                               int nb, int* __restrict__ blockoff) {
    __shared__ int lds[256];
    __shared__ int carry_s;
    int t = threadIdx.x;
    if (t == 0) carry_s = 0;
    __syncthreads();
    for (int base = 0; base < nb; base += 256) {
        int g = base + t;
        int v = (g < nb) ? blocksum[g] : 0;
        lds[t] = v;
        __syncthreads();
        for (int off = 1; off < 256; off <<= 1) {
            int x = (t >= off) ? lds[t - off] : 0;
            __syncthreads();
            lds[t] += x;
            __syncthreads();
        }
        if (g < nb) blockoff[g] = lds[t] - v + carry_s;
        __syncthreads();
        if (t == 255) carry_s += lds[255];
        __syncthreads();
    }
}

// combine -> transposed offsets: offsT[c*NBKT + b] (chunk-major, coalesced for scatter)
__global__ __launch_bounds__(256) void k_scanC(const int* __restrict__ presum,
                                               const int* __restrict__ hist,
                                               const int* __restrict__ blockoff,
                                               int n, int nchunk, int* __restrict__ offsT) {
    int g = blockIdx.x * 256 + threadIdx.x;
    if (g < n) {
        int val = presum[g] - hist[g] + blockoff[blockIdx.x];
        int b = g / nchunk;
        int c = g - b * nchunk;
        offsT[(size_t)c * NBKT + b] = val;
    }
}

// ---------------- stage 1: partition edges into buckets ----------------
// pack = (local_dst << 16) | src   (src < 65536, local_dst < 128)
__global__ __launch_bounds__(256) void k_scatter1(const int* __restrict__ src,
                                                  const int* __restrict__ dst, int E,
                                                  const int* __restrict__ offsT,
                                                  int* __restrict__ ebuf) {
    __shared__ int pos[NBKT];
    int t = threadIdx.x, blk = blockIdx.x;
    for (int b = t; b < NBKT; b += 256) pos[b] = offsT[(size_t)blk * NBKT + b];
    __syncthreads();
    int base = blk * CHUNK;
#pragma unroll
    for (int k = 0; k < EPT; ++k) {
        int e = base + k * 256 + t;
        if (e < E) {
            int d = dst[e];
            int b = d >> BSH;
            int p = atomicAdd(&pos[b], 1);
            ebuf[p] = ((d & (NPB - 1)) << 16) | src[e];
        }
    }
}

// ---------------- stage 2: per-bucket CSR (coalesced writes) ----------------
__global__ __launch_bounds__(256) void k_bucket_csr(const int* __restrict__ ebuf,
                                                    const int* __restrict__ offsT, int E,
                                                    int* __restrict__ rowstart,
                                                    int* __restrict__ colsrc) {
    __shared__ int cnt[NPB];
    __shared__ int s[NPB];
    __shared__ int pos2[NPB];
    __shared__ int lout[LDSE];
    int t = threadIdx.x, b = blockIdx.x;
    int bstart = offsT[b];
    int bend = (b + 1 < NBKT) ? offsT[b + 1] : E;
    int m = bend - bstart;
    if (t < NPB) cnt[t] = 0;
    __syncthreads();
    for (int i = bstart + t; i < bend; i += 256) atomicAdd(&cnt[ebuf[i] >> 16], 1);
    __syncthreads();
    if (t < NPB) s[t] = cnt[t];
    __syncthreads();
    for (int off = 1; off < NPB; off <<= 1) {
        int x = (t < NPB && t >= off) ? s[t - off] : 0;
        __syncthreads();
        if (t < NPB) s[t] += x;
        __syncthreads();
    }
    if (t < NPB) {
        int excl = s[t] - cnt[t];
        int node = b * NPB + t;
        if (node < NN) rowstart[node] = bstart + excl;
        pos2[t] = excl;
    }
    __syncthreads();
    if (m <= LDSE) {
        for (int i = bstart + t; i < bend; i += 256) {
            int v = ebuf[i];
            int p = atomicAdd(&pos2[v >> 16], 1);
            lout[p] = v & 0xFFFF;
        }
        __syncthreads();
        for (int i = t; i < m; i += 256) colsrc[bstart + i] = lout[i];
    } else {
        // overflow fallback (statistically unreachable): direct global scatter
        for (int i = bstart + t; i < bend; i += 256) {
            int v = ebuf[i];
            int p = atomicAdd(&pos2[v >> 16], 1);
            colsrc[bstart + p] = v & 0xFFFF;
        }
    }
    if (b == NBKT - 1 && t == 0) rowstart[NN] = E;
}

// ---------------- per-layer: node -> (q_s, q_d) in fp16 ----------------
__global__ __launch_bounds__(256) void k_q(
    const float* __restrict__ pin, int pstride, int c0, int c1, int c2,
    const float* __restrict__ W1l, const float* __restrict__ b1l,
    const float* __restrict__ scale, const float* __restrict__ shift, int use_bn,
    __half* __restrict__ qs, __half* __restrict__ qd) {
    int idx = blockIdx.x * 256 + threadIdx.x;   // v*64 + c
    int v = idx >> 6, c = idx & 63;
    const float* prow = pin + (size_t)v * pstride;
    float p0 = prow[c0], p1 = prow[c1], p2 = prow[c2];
    if (use_bn) {
        p0 = fmaxf(0.f, p0 * scale[0] + shift[0]);
        p1 = fmaxf(0.f, p1 * scale[1] + shift[1]);
        p2 = fmaxf(0.f, p2 * scale[2] + shift[2]);
    }
    float w0 = W1l[0 * 64 + c], w1 = W1l[1 * 64 + c], w2 = W1l[2 * 64 + c];
    float w3 = W1l[3 * 64 + c], w4 = W1l[4 * 64 + c], w5 = W1l[5 * 64 + c];
    qs[idx] = __float2half(p0 * w0 + p1 * w1 + p2 * w2);
    qd[idx] = __float2half(p0 * (w3 - w0) + p1 * (w4 - w1) + p2 * (w5 - w2) + b1l[c]);
}

// edge accumulation core: sum over incoming edges of relu(qs[src]+qd[v])
__device__ __forceinline__ float edge_accum(
    const __half* __restrict__ qs, float qdv, int lane,
    const int* __restrict__ colsrc, int start, int end) {
    float acc0 = 0.f, acc1 = 0.f;
    int i = start;
    while (i < end) {
        int cnt = min(64, end - i);
        int sl = (lane < cnt) ? colsrc[i + lane] : 0;
        int j = 0;
        for (; j + 8 <= cnt; j += 8) {
            int s0 = __shfl(sl, j),     s1 = __shfl(sl, j + 1);
            int s2 = __shfl(sl, j + 2), s3 = __shfl(sl, j + 3);
            int s4 = __shfl(sl, j + 4), s5 = __shfl(sl, j + 5);
            int s6 = __shfl(sl, j + 6), s7 = __shfl(sl, j + 7);
            float f0 = __half2float(qs[(size_t)s0 * 64 + lane]);
            float f1 = __half2float(qs[(size_t)s1 * 64 + lane]);
            float f2 = __half2float(qs[(size_t)s2 * 64 + lane]);
            float f3 = __half2float(qs[(size_t)s3 * 64 + lane]);
            float f4 = __half2float(qs[(size_t)s4 * 64 + lane]);
            float f5 = __half2float(qs[(size_t)s5 * 64 + lane]);
            float f6 = __half2float(qs[(size_t)s6 * 64 + lane]);
            float f7 = __half2float(qs[(size_t)s7 * 64 + lane]);
            acc0 += fmaxf(0.f, f0 + qdv);
            acc1 += fmaxf(0.f, f1 + qdv);
            acc0 += fmaxf(0.f, f2 + qdv);
            acc1 += fmaxf(0.f, f3 + qdv);
            acc0 += fmaxf(0.f, f4 + qdv);
            acc1 += fmaxf(0.f, f5 + qdv);
            acc0 += fmaxf(0.f, f6 + qdv);
            acc1 += fmaxf(0.f, f7 + qdv);
        }
        for (; j < cnt; ++j) {
            int sx = __shfl(sl, j);
            acc0 += fmaxf(0.f, __half2float(qs[(size_t)sx * 64 + lane]) + qdv);
        }
        i += cnt;
    }
    return acc0 + acc1;
}

// ---------------- gather + reduce, layers 0..4 (3 output cols) ----------------
__global__ __launch_bounds__(256) void k_gather3(
    const __half* __restrict__ qs, const __half* __restrict__ qd,
    const int* __restrict__ rowstart, const int* __restrict__ colsrc,
    const float* __restrict__ W2l, const float* __restrict__ b2l,
    float* __restrict__ pnext, float* __restrict__ partials) {
    int tid = threadIdx.x;
    int w = tid >> 6, lane = tid & 63;
    int v = blockIdx.x * 4 + w;
    float qdv = __half2float(qd[v * 64 + lane]);
    int start = rowstart[v], end = rowstart[v + 1];
    float acc = fmaxf(0.f, __half2float(qs[v * 64 + lane]) + qdv);   // self loop
    acc += edge_accum(qs, qdv, lane, colsrc, start, end);
    float degp1 = (float)(end - start + 1);
    __shared__ float part[4][8];
    const int cols[3] = {0, 1, 14};
#pragma unroll
    for (int j = 0; j < 3; ++j) {
        float t = acc * W2l[lane * 64 + cols[j]];
        for (int off = 32; off; off >>= 1) t += __shfl_xor(t, off);
        if (lane == 0) {
            float val = t + degp1 * b2l[cols[j]];
            pnext[v * 3 + j] = val;
            part[w][j] = val;
            part[w][3 + j] = val * val;
        }
    }
    __syncthreads();
    if (tid < 6) {
        float ssum = part[0][tid] + part[1][tid] + part[2][tid] + part[3][tid];
        partials[blockIdx.x * 8 + tid] = ssum;
    }
}

// ---------------- BN finalize (3 cols): partials -> scale/shift ----------------
__global__ void k_bnfin(const float* __restrict__ partials, int nb,
                        const float* __restrict__ gamma_l, const float* __restrict__ beta_l,
                        float* __restrict__ scale, float* __restrict__ shift) {
    __shared__ float lds[256][6];
    int t = threadIdx.x;
    float s[6] = {0, 0, 0, 0, 0, 0};
    for (int b = t; b < nb; b += 256)
        for (int j = 0; j < 6; ++j) s[j] += partials[b * 8 + j];
    for (int j = 0; j < 6; ++j) lds[t][j] = s[j];
    __syncthreads();
    for (int off = 128; off; off >>= 1) {
        if (t < off)
            for (int j = 0; j < 6; ++j) lds[t][j] += lds[t + off][j];
        __syncthreads();
    }
    if (t < 3) {
        const int cols[3] = {0, 1, 14};
        float mu = lds[0][t] / (float)NN;
        float var = lds[0][t + 3] / (float)NN - mu * mu;
        float rs = rsqrtf(var + EPSV);
        float g = gamma_l[cols[t]];
        scale[t] = rs * g;
        shift[t] = beta_l[cols[t]] - mu * rs * g;
    }
}

// ---------------- gather + full 64-col matmul, layer 5 ----------------
__global__ __launch_bounds__(256) void k_gather_full(
    const __half* __restrict__ qs, const __half* __restrict__ qd,
    const int* __restrict__ rowstart, const int* __restrict__ colsrc,
    const float* __restrict__ W2l, const float* __restrict__ b2l,
    float* __restrict__ out) {
    int tid = threadIdx.x;
    int w = tid >> 6, lane = tid & 63;
    int v = blockIdx.x * 4 + w;
    float qdv = __half2float(qd[v * 64 + lane]);
    int start = rowstart[v], end = rowstart[v + 1];
    float acc = fmaxf(0.f, __half2float(qs[v * 64 + lane]) + qdv);   // self loop
    acc += edge_accum(qs, qdv, lane, colsrc, start, end);
    __shared__ float lds[4][64];
    lds[w][lane] = acc;
    __syncthreads();
    float degp1 = (float)(end - start + 1);
    float sum = degp1 * b2l[lane];
    for (int k = 0; k < 64; ++k) sum += lds[w][k] * W2l[k * 64 + lane];
    out[v * 64 + lane] = sum;
}

// ---------------- launch ----------------

static inline size_t align_up(size_t x) { return (x + 255) & ~(size_t)255; }

extern "C" void kernel_launch(void* const* d_in, const int* in_sizes, int n_in,
                              void* d_out, int out_size, void* d_ws, size_t ws_size,
                              hipStream_t stream) {
    const float* x     = (const float*)d_in[0];
    const int*   ei    = (const int*)d_in[1];
    const float* W1    = (const float*)d_in[2];
    const float* b1    = (const float*)d_in[3];
    const float* W2    = (const float*)d_in[4];
    const float* b2    = (const float*)d_in[5];
    const float* gamma = (const float*)d_in[6];
    const float* beta  = (const float*)d_in[7];
    float* out = (float*)d_out;
    const int E = in_sizes[1] / 2;           // 1,600,000
    const int* src = ei;
    const int* dst = ei + E;

    const int nchunk = (E + CHUNK - 1) / CHUNK;     // 391
    const int nscan  = NBKT * nchunk;               // ~152,881
    const int nsb    = (nscan + 255) / 256;         // ~598

    // workspace carve
    char* base = (char*)d_ws;
    size_t off = 0;
    __half* qs = (__half*)(base + off);     off = align_up(off + (size_t)NN * 64 * 2);
    __half* qd = (__half*)(base + off);     off = align_up(off + (size_t)NN * 64 * 2);
    float* pA = (float*)(base + off);       off = align_up(off + (size_t)NN * 3 * 4);
    float* pB = (float*)(base + off);       off = align_up(off + (size_t)NN * 3 * 4);
    int* rowstart = (int*)(base + off);     off = align_up(off + (size_t)(NN + 1) * 4);
    int* colsrc   = (int*)(base + off);     off = align_up(off + (size_t)E * 4);
    int* ebuf     = (int*)(base + off);     off = align_up(off + (size_t)E * 4);
    int* hist     = (int*)(base + off);     off = align_up(off + (size_t)nscan * 4);
    int* offsT    = (int*)(base + off);     off = align_up(off + (size_t)nscan * 4);
    int* presum   = (int*)(base + off);     off = align_up(off + (size_t)nscan * 4);
    int* bsum     = (int*)(base + off);     off = align_up(off + (size_t)nsb * 4);
    int* boff     = (int*)(base + off);     off = align_up(off + (size_t)nsb * 4);
    float* partials = (float*)(base + off); off = align_up(off + (size_t)NBLK * 8 * 4);
    float* scale = (float*)(base + off);    off = align_up(off + 64 * 4);
    float* shift = (float*)(base + off);    off = align_up(off + 64 * 4);
    (void)ws_size; (void)n_in; (void)out_size;

    // CSR build: two-stage counting sort, no global atomics
    k_hist1<<<nchunk, 256, 0, stream>>>(dst, E, nchunk, hist);
    k_scanA<<<nsb, 256, 0, stream>>>(hist, nscan, presum, bsum);
    k_scanB<<<1, 256, 0, stream>>>(bsum, nsb, boff);
    k_scanC<<<nsb, 256, 0, stream>>>(presum, hist, boff, nscan, nchunk, offsT);
    k_scatter1<<<nchunk, 256, 0, stream>>>(src, dst, E, offsT, ebuf);
    k_bucket_csr<<<NBKT, 256, 0, stream>>>(ebuf, offsT, E, rowstart, colsrc);

    float* pc = pA;
    float* pn = pB;
    for (int l = 0; l < 6; ++l) {
        const float* pin = (l == 0) ? x : pc;
        int pstride = (l == 0) ? 16 : 3;
        int c0 = 0, c1 = 1, c2 = (l == 0) ? 14 : 2;
        k_q<<<NBLK, 256, 0, stream>>>(pin, pstride, c0, c1, c2,
                                      W1 + (size_t)l * 6 * 64, b1 + (size_t)l * 64,
                                      scale, shift, (l > 0) ? 1 : 0, qs, qd);
        if (l < 5) {
            k_gather3<<<NBLK, 256, 0, stream>>>(qs, qd, rowstart, colsrc,
                                                W2 + (size_t)l * 64 * 64, b2 + (size_t)l * 64,
                                                pn, partials);
            k_bnfin<<<1, 256, 0, stream>>>(partials, NBLK,
                                           gamma + (size_t)l * 64, beta + (size_t)l * 64,
                                           scale, shift);
            float* tmp = pc; pc = pn; pn = tmp;
        } else {
            k_gather_full<<<NBLK, 256, 0, stream>>>(qs, qd, rowstart, colsrc,
                                                    W2 + (size_t)5 * 64 * 64, b2 + (size_t)5 * 64,
                                                    out);
        }
    }
}

// Round 5
// 527.945 us; speedup vs baseline: 2.2392x; 1.0876x over previous
//
#include <hip/hip_runtime.h>
#include <hip/hip_fp16.h>
#include <cstdint>

#define NN 50000
#define NBLK 12500              // NN/4 nodes per 256-thread block (4 waves)
#define EPSV 1e-5f

// bucket sort params
#define NPB 128                 // nodes per bucket
#define BSH 7                   // log2(NPB)
#define NBKT 391                // ceil(NN/NPB)
#define CHUNK 4096              // edges per stage-1 block
#define EPT 16                  // edges per thread (CHUNK/256)
#define LDSE 6144               // per-bucket LDS edge capacity (mean ~4096, 32 sigma)

typedef unsigned short ushort_t;
typedef _Float16 half2v __attribute__((ext_vector_type(2)));

// ---------------- stage 1: per-chunk bucket histogram ----------------
__global__ __launch_bounds__(256) void k_hist1(const int* __restrict__ dst, int E, int nchunk,
                                               int* __restrict__ hist) {
    __shared__ int cnt[NBKT];
    int t = threadIdx.x, blk = blockIdx.x;
    for (int b = t; b < NBKT; b += 256) cnt[b] = 0;
    __syncthreads();
    int base = blk * CHUNK;
#pragma unroll
    for (int k = 0; k < EPT; ++k) {
        int e = base + k * 256 + t;
        if (e < E) atomicAdd(&cnt[dst[e] >> BSH], 1);
    }
    __syncthreads();
    for (int b = t; b < NBKT; b += 256) hist[(size_t)b * nchunk + blk] = cnt[b];
}

// ---------------- generic hierarchical exclusive scan ----------------
__global__ __launch_bounds__(256) void k_scanA(const int* __restrict__ in, int n,
                                               int* __restrict__ presum, int* __restrict__ blocksum) {
    __shared__ int lds[256];
    int t = threadIdx.x, g = blockIdx.x * 256 + t;
    int v = (g < n) ? in[g] : 0;
    lds[t] = v;
    __syncthreads();
    for (int off = 1; off < 256; off <<= 1) {
        int x = (t >= off) ? lds[t - off] : 0;
        __syncthreads();
        lds[t] += x;
        __syncthreads();
    }
    if (g < n) presum[g] = lds[t];               // block-local inclusive
    if (t == 255) blocksum[blockIdx.x] = lds[255];
}

// single-block loop-carried exclusive scan of nb block sums
__global__ __launch_bounds__(256) void k_scanB(const int* __restrict__ blocksum,
                                               int nb, int* __restrict__ blockoff) {
    __shared__ int lds[256];
    __shared__ int carry_s;
    int t = threadIdx.x;
    if (t == 0) carry_s = 0;
    __syncthreads();
    for (int base = 0; base < nb; base += 256) {
        int g = base + t;
        int v = (g < nb) ? blocksum[g] : 0;
        lds[t] = v;
        __syncthreads();
        for (int off = 1; off < 256; off <<= 1) {
            int x = (t >= off) ? lds[t - off] : 0;
            __syncthreads();
            lds[t] += x;
            __syncthreads();
        }
        if (g < nb) blockoff[g] = lds[t] - v + carry_s;
        __syncthreads();
        if (t == 255) carry_s += lds[255];
        __syncthreads();
    }
}

// combine -> transposed offsets: offsT[c*NBKT + b] (chunk-major, coalesced for scatter)
__global__ __launch_bounds__(256) void k_scanC(const int* __restrict__ presum,
                                               const int* __restrict__ hist,
                                               const int* __restrict__ blockoff,
                                               int n, int nchunk, int* __restrict__ offsT) {
    int g = blockIdx.x * 256 + threadIdx.x;
    if (g < n) {
        int val = presum[g] - hist[g] + blockoff[blockIdx.x];
        int b = g / nchunk;
        int c = g - b * nchunk;
        offsT[(size_t)c * NBKT + b] = val;
    }
}

// ---------------- stage 1: partition edges into buckets ----------------
// pack = (local_dst << 16) | src   (src < 65536, local_dst < 128)
__global__ __launch_bounds__(256) void k_scatter1(const int* __restrict__ src,
                                                  const int* __restrict__ dst, int E,
                                                  const int* __restrict__ offsT,
                                                  int* __restrict__ ebuf) {
    __shared__ int pos[NBKT];
    int t = threadIdx.x, blk = blockIdx.x;
    for (int b = t; b < NBKT; b += 256) pos[b] = offsT[(size_t)blk * NBKT + b];
    __syncthreads();
    int base = blk * CHUNK;
#pragma unroll
    for (int k = 0; k < EPT; ++k) {
        int e = base + k * 256 + t;
        if (e < E) {
            int d = dst[e];
            int b = d >> BSH;
            int p = atomicAdd(&pos[b], 1);
            ebuf[p] = ((d & (NPB - 1)) << 16) | src[e];
        }
    }
}

// ---------------- stage 2: per-bucket CSR (coalesced writes, ushort colsrc) ----------------
__global__ __launch_bounds__(256) void k_bucket_csr(const int* __restrict__ ebuf,
                                                    const int* __restrict__ offsT, int E,
                                                    int* __restrict__ rowstart,
                                                    ushort_t* __restrict__ colsrc) {
    __shared__ int cnt[NPB];
    __shared__ int s[NPB];
    __shared__ int pos2[NPB];
    __shared__ ushort_t lout[LDSE];
    int t = threadIdx.x, b = blockIdx.x;
    int bstart = offsT[b];
    int bend = (b + 1 < NBKT) ? offsT[b + 1] : E;
    int m = bend - bstart;
    if (t < NPB) cnt[t] = 0;
    __syncthreads();
    for (int i = bstart + t; i < bend; i += 256) atomicAdd(&cnt[ebuf[i] >> 16], 1);
    __syncthreads();
    if (t < NPB) s[t] = cnt[t];
    __syncthreads();
    for (int off = 1; off < NPB; off <<= 1) {
        int x = (t < NPB && t >= off) ? s[t - off] : 0;
        __syncthreads();
        if (t < NPB) s[t] += x;
        __syncthreads();
    }
    if (t < NPB) {
        int excl = s[t] - cnt[t];
        int node = b * NPB + t;
        if (node < NN) rowstart[node] = bstart + excl;
        pos2[t] = excl;
    }
    __syncthreads();
    if (m <= LDSE) {
        for (int i = bstart + t; i < bend; i += 256) {
            int v = ebuf[i];
            int p = atomicAdd(&pos2[v >> 16], 1);
            lout[p] = (ushort_t)(v & 0xFFFF);
        }
        __syncthreads();
        for (int i = t; i < m; i += 256) colsrc[bstart + i] = lout[i];
    } else {
        // overflow fallback (statistically unreachable): direct global scatter
        for (int i = bstart + t; i < bend; i += 256) {
            int v = ebuf[i];
            int p = atomicAdd(&pos2[v >> 16], 1);
            colsrc[bstart + p] = (ushort_t)(v & 0xFFFF);
        }
    }
    if (b == NBKT - 1 && t == 0) rowstart[NN] = E;
}

// ---------------- per-layer: node -> (q_s, q_d) in fp16 ----------------
__global__ __launch_bounds__(256) void k_q(
    const float* __restrict__ pin, int pstride, int c0, int c1, int c2,
    const float* __restrict__ W1l, const float* __restrict__ b1l,
    const float* __restrict__ scale, const float* __restrict__ shift, int use_bn,
    __half* __restrict__ qs, __half* __restrict__ qd) {
    int idx = blockIdx.x * 256 + threadIdx.x;   // v*64 + c
    int v = idx >> 6, c = idx & 63;
    const float* prow = pin + (size_t)v * pstride;
    float p0 = prow[c0], p1 = prow[c1], p2 = prow[c2];
    if (use_bn) {
        p0 = fmaxf(0.f, p0 * scale[0] + shift[0]);
        p1 = fmaxf(0.f, p1 * scale[1] + shift[1]);
        p2 = fmaxf(0.f, p2 * scale[2] + shift[2]);
    }
    float w0 = W1l[0 * 64 + c], w1 = W1l[1 * 64 + c], w2 = W1l[2 * 64 + c];
    float w3 = W1l[3 * 64 + c], w4 = W1l[4 * 64 + c], w5 = W1l[5 * 64 + c];
    qs[idx] = __float2half(p0 * w0 + p1 * w1 + p2 * w2);
    qd[idx] = __float2half(p0 * (w3 - w0) + p1 * (w4 - w1) + p2 * (w5 - w2) + b1l[c]);
}

// ---------------- vectorized edge accumulation ----------------
// lane L: edge-slot es=L>>3, channel-group cg=L&7 (channels cg*8 .. cg*8+7)
// one dwordx4 load = 8 halves = one edge-slot's channel group; 8 edges/instr/wave.
__device__ __forceinline__ half2v bitcast_h2(unsigned int u) {
    union { unsigned int u; half2v h; } cvt;
    cvt.u = u;
    return cvt.h;
}

__device__ __forceinline__ void accum8(const uint4* __restrict__ qsrow, int s, int cg,
                                       const half2v qd2[4], float acc[8]) {
    uint4 q = qsrow[(size_t)s * 8 + cg];
    unsigned int wd[4] = {q.x, q.y, q.z, q.w};
    const half2v z2 = {(_Float16)0.0f, (_Float16)0.0f};
#pragma unroll
    for (int d = 0; d < 4; ++d) {
        half2v r = bitcast_h2(wd[d]) + qd2[d];          // v_pk_add_f16
        r = __builtin_elementwise_max(r, z2);           // v_pk_max_f16
        acc[2 * d]     += (float)r.x;
        acc[2 * d + 1] += (float)r.y;
    }
}

__device__ __forceinline__ void accum8_masked(const uint4* __restrict__ qsrow, int s, int cg,
                                              const half2v qd2[4], float acc[8], bool ok) {
    uint4 q = qsrow[(size_t)s * 8 + cg];
    unsigned int wd[4] = {q.x, q.y, q.z, q.w};
    const half2v z2 = {(_Float16)0.0f, (_Float16)0.0f};
#pragma unroll
    for (int d = 0; d < 4; ++d) {
        half2v r = bitcast_h2(wd[d]) + qd2[d];
        r = __builtin_elementwise_max(r, z2);
        acc[2 * d]     += ok ? (float)r.x : 0.0f;
        acc[2 * d + 1] += ok ? (float)r.y : 0.0f;
    }
}

// edge loop: fills acc[8] (per-lane partial sums, to be butterflied over es)
__device__ __forceinline__ void edge_loop(const uint4* __restrict__ qsrow,
                                          const ushort_t* __restrict__ colsrc,
                                          int start, int end, int es, int cg,
                                          const half2v qd2[4], float acc[8]) {
    int lane = (es << 3) | cg;
    int i = start;
    while (i < end) {
        int cnt = min(64, end - i);
        int sl = (lane < cnt) ? (int)colsrc[i + lane] : 0;
        int nfull = cnt & ~7;
        int j = 0;
        for (; j < nfull; j += 8) {
            int s = __shfl(sl, j + es);
            accum8(qsrow, s, cg, qd2, acc);
        }
        if (j < cnt) {
            int slot = j + es;
            int s = __shfl(sl, slot);
            accum8_masked(qsrow, s, cg, qd2, acc, slot < cnt);
        }
        i += cnt;
    }
}

// ---------------- gather + reduce, layers 0..4 (3 output cols) ----------------
__global__ __launch_bounds__(256) void k_gather3(
    const __half* __restrict__ qs, const __half* __restrict__ qd,
    const int* __restrict__ rowstart, const ushort_t* __restrict__ colsrc,
    const float* __restrict__ W2l, const float* __restrict__ b2l,
    float* __restrict__ pnext, float* __restrict__ partials) {
    __shared__ float w2c[3][64];
    __shared__ float b2c[3];
    __shared__ float part[4][8];
    int tid = threadIdx.x;
    if (tid < 192) {
        int cj = tid >> 6;
        int col = (cj == 0) ? 0 : ((cj == 1) ? 1 : 14);
        w2c[cj][tid & 63] = W2l[(tid & 63) * 64 + col];
    }
    if (tid < 3) b2c[tid] = b2l[(tid == 0) ? 0 : ((tid == 1) ? 1 : 14)];
    __syncthreads();

    int w = tid >> 6, lane = tid & 63;
    int es = lane >> 3, cg = lane & 7;
    int v = blockIdx.x * 4 + w;
    const uint4* qsrow = (const uint4*)qs;
    uint4 qq = ((const uint4*)qd)[(size_t)v * 8 + cg];
    unsigned int qw[4] = {qq.x, qq.y, qq.z, qq.w};
    half2v qd2[4];
#pragma unroll
    for (int d = 0; d < 4; ++d) qd2[d] = bitcast_h2(qw[d]);

    float acc[8] = {0, 0, 0, 0, 0, 0, 0, 0};
    int start = rowstart[v], end = rowstart[v + 1];
    if (es == 0) accum8(qsrow, v, cg, qd2, acc);        // self loop
    edge_loop(qsrow, colsrc, start, end, es, cg, qd2, acc);

    // fold the 8 edge-slots
#pragma unroll
    for (int k = 0; k < 8; ++k) {
        acc[k] += __shfl_xor(acc[k], 8);
        acc[k] += __shfl_xor(acc[k], 16);
        acc[k] += __shfl_xor(acc[k], 32);
    }
    float degp1 = (float)(end - start + 1);
#pragma unroll
    for (int j = 0; j < 3; ++j) {
        float t = 0.f;
#pragma unroll
        for (int k = 0; k < 8; ++k) t += acc[k] * w2c[j][cg * 8 + k];
        t += __shfl_xor(t, 1);
        t += __shfl_xor(t, 2);
        t += __shfl_xor(t, 4);
        if (lane == 0) {
            float val = t + degp1 * b2c[j];
            pnext[v * 3 + j] = val;
            part[w][j] = val;
            part[w][3 + j] = val * val;
        }
    }
    __syncthreads();
    if (tid < 6) {
        float ssum = part[0][tid] + part[1][tid] + part[2][tid] + part[3][tid];
        partials[blockIdx.x * 8 + tid] = ssum;
    }
}

// ---------------- BN finalize (3 cols): partials -> scale/shift ----------------
__global__ void k_bnfin(const float* __restrict__ partials, int nb,
                        const float* __restrict__ gamma_l, const float* __restrict__ beta_l,
                        float* __restrict__ scale, float* __restrict__ shift) {
    __shared__ float lds[256][6];
    int t = threadIdx.x;
    float s[6] = {0, 0, 0, 0, 0, 0};
    for (int b = t; b < nb; b += 256)
        for (int j = 0; j < 6; ++j) s[j] += partials[b * 8 + j];
    for (int j = 0; j < 6; ++j) lds[t][j] = s[j];
    __syncthreads();
    for (int off = 128; off; off >>= 1) {
        if (t < off)
            for (int j = 0; j < 6; ++j) lds[t][j] += lds[t + off][j];
        __syncthreads();
    }
    if (t < 3) {
        const int cols[3] = {0, 1, 14};
        float mu = lds[0][t] / (float)NN;
        float var = lds[0][t + 3] / (float)NN - mu * mu;
        float rs = rsqrtf(var + EPSV);
        float g = gamma_l[cols[t]];
        scale[t] = rs * g;
        shift[t] = beta_l[cols[t]] - mu * rs * g;
    }
}

// ---------------- gather + full 64-col matmul, layer 5 ----------------
__global__ __launch_bounds__(256) void k_gather_full(
    const __half* __restrict__ qs, const __half* __restrict__ qd,
    const int* __restrict__ rowstart, const ushort_t* __restrict__ colsrc,
    const float* __restrict__ W2l, const float* __restrict__ b2l,
    float* __restrict__ out) {
    __shared__ float lds[4][64];
    int tid = threadIdx.x;
    int w = tid >> 6, lane = tid & 63;
    int es = lane >> 3, cg = lane & 7;
    int v = blockIdx.x * 4 + w;
    const uint4* qsrow = (const uint4*)qs;
    uint4 qq = ((const uint4*)qd)[(size_t)v * 8 + cg];
    unsigned int qw[4] = {qq.x, qq.y, qq.z, qq.w};
    half2v qd2[4];
#pragma unroll
    for (int d = 0; d < 4; ++d) qd2[d] = bitcast_h2(qw[d]);

    float acc[8] = {0, 0, 0, 0, 0, 0, 0, 0};
    int start = rowstart[v], end = rowstart[v + 1];
    if (es == 0) accum8(qsrow, v, cg, qd2, acc);        // self loop
    edge_loop(qsrow, colsrc, start, end, es, cg, qd2, acc);

#pragma unroll
    for (int k = 0; k < 8; ++k) {
        acc[k] += __shfl_xor(acc[k], 8);
        acc[k] += __shfl_xor(acc[k], 16);
        acc[k] += __shfl_xor(acc[k], 32);
    }
    if (es == 0) {
#pragma unroll
        for (int k = 0; k < 8; ++k) lds[w][cg * 8 + k] = acc[k];
    }
    __syncthreads();
    float degp1 = (float)(end - start + 1);
    float sum = degp1 * b2l[lane];
    for (int k = 0; k < 64; ++k) sum += lds[w][k] * W2l[k * 64 + lane];
    out[v * 64 + lane] = sum;
}

// ---------------- launch ----------------

static inline size_t align_up(size_t x) { return (x + 255) & ~(size_t)255; }

extern "C" void kernel_launch(void* const* d_in, const int* in_sizes, int n_in,
                              void* d_out, int out_size, void* d_ws, size_t ws_size,
                              hipStream_t stream) {
    const float* x     = (const float*)d_in[0];
    const int*   ei    = (const int*)d_in[1];
    const float* W1    = (const float*)d_in[2];
    const float* b1    = (const float*)d_in[3];
    const float* W2    = (const float*)d_in[4];
    const float* b2    = (const float*)d_in[5];
    const float* gamma = (const float*)d_in[6];
    const float* beta  = (const float*)d_in[7];
    float* out = (float*)d_out;
    const int E = in_sizes[1] / 2;           // 1,600,000
    const int* src = ei;
    const int* dst = ei + E;

    const int nchunk = (E + CHUNK - 1) / CHUNK;     // 391
    const int nscan  = NBKT * nchunk;               // ~152,881
    const int nsb    = (nscan + 255) / 256;         // ~598

    // workspace carve
    char* base = (char*)d_ws;
    size_t off = 0;
    __half* qs = (__half*)(base + off);     off = align_up(off + (size_t)NN * 64 * 2);
    __half* qd = (__half*)(base + off);     off = align_up(off + (size_t)NN * 64 * 2);
    float* pA = (float*)(base + off);       off = align_up(off + (size_t)NN * 3 * 4);
    float* pB = (float*)(base + off);       off = align_up(off + (size_t)NN * 3 * 4);
    int* rowstart = (int*)(base + off);     off = align_up(off + (size_t)(NN + 1) * 4);
    ushort_t* colsrc = (ushort_t*)(base + off); off = align_up(off + (size_t)E * 2);
    int* ebuf     = (int*)(base + off);     off = align_up(off + (size_t)E * 4);
    int* hist     = (int*)(base + off);     off = align_up(off + (size_t)nscan * 4);
    int* offsT    = (int*)(base + off);     off = align_up(off + (size_t)nscan * 4);
    int* presum   = (int*)(base + off);     off = align_up(off + (size_t)nscan * 4);
    int* bsum     = (int*)(base + off);     off = align_up(off + (size_t)nsb * 4);
    int* boff     = (int*)(base + off);     off = align_up(off + (size_t)nsb * 4);
    float* partials = (float*)(base + off); off = align_up(off + (size_t)NBLK * 8 * 4);
    float* scale = (float*)(base + off);    off = align_up(off + 64 * 4);
    float* shift = (float*)(base + off);    off = align_up(off + 64 * 4);
    (void)ws_size; (void)n_in; (void)out_size;

    // CSR build: two-stage counting sort, no global atomics
    k_hist1<<<nchunk, 256, 0, stream>>>(dst, E, nchunk, hist);
    k_scanA<<<nsb, 256, 0, stream>>>(hist, nscan, presum, bsum);
    k_scanB<<<1, 256, 0, stream>>>(bsum, nsb, boff);
    k_scanC<<<nsb, 256, 0, stream>>>(presum, hist, boff, nscan, nchunk, offsT);
    k_scatter1<<<nchunk, 256, 0, stream>>>(src, dst, E, offsT, ebuf);
    k_bucket_csr<<<NBKT, 256, 0, stream>>>(ebuf, offsT, E, rowstart, colsrc);

    float* pc = pA;
    float* pn = pB;
    for (int l = 0; l < 6; ++l) {
        const float* pin = (l == 0) ? x : pc;
        int pstride = (l == 0) ? 16 : 3;
        int c0 = 0, c1 = 1, c2 = (l == 0) ? 14 : 2;
        k_q<<<NBLK, 256, 0, stream>>>(pin, pstride, c0, c1, c2,
                                      W1 + (size_t)l * 6 * 64, b1 + (size_t)l * 64,
                                      scale, shift, (l > 0) ? 1 : 0, qs, qd);
        if (l < 5) {
            k_gather3<<<NBLK, 256, 0, stream>>>(qs, qd, rowstart, colsrc,
                                                W2 + (size_t)l * 64 * 64, b2 + (size_t)l * 64,
                                                pn, partials);
            k_bnfin<<<1, 256, 0, stream>>>(partials, NBLK,
                                           gamma + (size_t)l * 64, beta + (size_t)l * 64,
                                           scale, shift);
            float* tmp = pc; pc = pn; pn = tmp;
        } else {
            k_gather_full<<<NBLK, 256, 0, stream>>>(qs, qd, rowstart, colsrc,
                                                    W2 + (size_t)5 * 64 * 64, b2 + (size_t)5 * 64,
                                                    out);
        }
    }
}

// Round 6
// 526.315 us; speedup vs baseline: 2.2462x; 1.0031x over previous
//
#include <hip/hip_runtime.h>
#include <hip/hip_fp16.h>
#include <cstdint>

#define NN 50000
#define NBLK 12500              // NN/4 nodes per 256-thread block (4 waves)
#define EPSV 1e-5f

// bucket sort params
#define NPB 128                 // nodes per bucket
#define BSH 7                   // log2(NPB)
#define NBKT 391                // ceil(NN/NPB)
#define CHUNK 4096              // edges per stage-1 block
#define EPT 16                  // edges per thread (CHUNK/256)
#define LDSE 6144               // per-bucket LDS edge capacity (mean ~4096, 32 sigma)

typedef unsigned short ushort_t;
typedef _Float16 half2v __attribute__((ext_vector_type(2)));

// ---------------- stage 1: per-chunk bucket histogram ----------------
__global__ __launch_bounds__(256) void k_hist1(const int* __restrict__ dst, int E, int nchunk,
                                               int* __restrict__ hist) {
    __shared__ int cnt[NBKT];
    int t = threadIdx.x, blk = blockIdx.x;
    for (int b = t; b < NBKT; b += 256) cnt[b] = 0;
    __syncthreads();
    int base = blk * CHUNK;
#pragma unroll
    for (int k = 0; k < EPT; ++k) {
        int e = base + k * 256 + t;
        if (e < E) atomicAdd(&cnt[dst[e] >> BSH], 1);
    }
    __syncthreads();
    for (int b = t; b < NBKT; b += 256) hist[(size_t)b * nchunk + blk] = cnt[b];
}

// ---------------- generic hierarchical exclusive scan ----------------
__global__ __launch_bounds__(256) void k_scanA(const int* __restrict__ in, int n,
                                               int* __restrict__ presum, int* __restrict__ blocksum) {
    __shared__ int lds[256];
    int t = threadIdx.x, g = blockIdx.x * 256 + t;
    int v = (g < n) ? in[g] : 0;
    lds[t] = v;
    __syncthreads();
    for (int off = 1; off < 256; off <<= 1) {
        int x = (t >= off) ? lds[t - off] : 0;
        __syncthreads();
        lds[t] += x;
        __syncthreads();
    }
    if (g < n) presum[g] = lds[t];               // block-local inclusive
    if (t == 255) blocksum[blockIdx.x] = lds[255];
}

// single-block loop-carried exclusive scan of nb block sums
__global__ __launch_bounds__(256) void k_scanB(const int* __restrict__ blocksum,
                                               int nb, int* __restrict__ blockoff) {
    __shared__ int lds[256];
    __shared__ int carry_s;
    int t = threadIdx.x;
    if (t == 0) carry_s = 0;
    __syncthreads();
    for (int base = 0; base < nb; base += 256) {
        int g = base + t;
        int v = (g < nb) ? blocksum[g] : 0;
        lds[t] = v;
        __syncthreads();
        for (int off = 1; off < 256; off <<= 1) {
            int x = (t >= off) ? lds[t - off] : 0;
            __syncthreads();
            lds[t] += x;
            __syncthreads();
        }
        if (g < nb) blockoff[g] = lds[t] - v + carry_s;
        __syncthreads();
        if (t == 255) carry_s += lds[255];
        __syncthreads();
    }
}

// combine -> transposed offsets: offsT[c*NBKT + b] (chunk-major, coalesced for scatter)
__global__ __launch_bounds__(256) void k_scanC(const int* __restrict__ presum,
                                               const int* __restrict__ hist,
                                               const int* __restrict__ blockoff,
                                               int n, int nchunk, int* __restrict__ offsT) {
    int g = blockIdx.x * 256 + threadIdx.x;
    if (g < n) {
        int val = presum[g] - hist[g] + blockoff[blockIdx.x];
        int b = g / nchunk;
        int c = g - b * nchunk;
        offsT[(size_t)c * NBKT + b] = val;
    }
}

// ---------------- stage 1: partition edges into buckets ----------------
// pack = (local_dst << 16) | src   (src < 65536, local_dst < 128)
__global__ __launch_bounds__(256) void k_scatter1(const int* __restrict__ src,
                                                  const int* __restrict__ dst, int E,
                                                  const int* __restrict__ offsT,
                                                  int* __restrict__ ebuf) {
    __shared__ int pos[NBKT];
    int t = threadIdx.x, blk = blockIdx.x;
    for (int b = t; b < NBKT; b += 256) pos[b] = offsT[(size_t)blk * NBKT + b];
    __syncthreads();
    int base = blk * CHUNK;
#pragma unroll
    for (int k = 0; k < EPT; ++k) {
        int e = base + k * 256 + t;
        if (e < E) {
            int d = dst[e];
            int b = d >> BSH;
            int p = atomicAdd(&pos[b], 1);
            ebuf[p] = ((d & (NPB - 1)) << 16) | src[e];
        }
    }
}

// ---------------- stage 2: per-bucket CSR (coalesced writes, ushort colsrc) ----------------
__global__ __launch_bounds__(256) void k_bucket_csr(const int* __restrict__ ebuf,
                                                    const int* __restrict__ offsT, int E,
                                                    int* __restrict__ rowstart,
                                                    ushort_t* __restrict__ colsrc) {
    __shared__ int cnt[NPB];
    __shared__ int s[NPB];
    __shared__ int pos2[NPB];
    __shared__ ushort_t lout[LDSE];
    int t = threadIdx.x, b = blockIdx.x;
    int bstart = offsT[b];
    int bend = (b + 1 < NBKT) ? offsT[b + 1] : E;
    int m = bend - bstart;
    if (t < NPB) cnt[t] = 0;
    __syncthreads();
    for (int i = bstart + t; i < bend; i += 256) atomicAdd(&cnt[ebuf[i] >> 16], 1);
    __syncthreads();
    if (t < NPB) s[t] = cnt[t];
    __syncthreads();
    for (int off = 1; off < NPB; off <<= 1) {
        int x = (t < NPB && t >= off) ? s[t - off] : 0;
        __syncthreads();
        if (t < NPB) s[t] += x;
        __syncthreads();
    }
    if (t < NPB) {
        int excl = s[t] - cnt[t];
        int node = b * NPB + t;
        if (node < NN) rowstart[node] = bstart + excl;
        pos2[t] = excl;
    }
    __syncthreads();
    if (m <= LDSE) {
        for (int i = bstart + t; i < bend; i += 256) {
            int v = ebuf[i];
            int p = atomicAdd(&pos2[v >> 16], 1);
            lout[p] = (ushort_t)(v & 0xFFFF);
        }
        __syncthreads();
        for (int i = t; i < m; i += 256) colsrc[bstart + i] = lout[i];
    } else {
        // overflow fallback (statistically unreachable): direct global scatter
        for (int i = bstart + t; i < bend; i += 256) {
            int v = ebuf[i];
            int p = atomicAdd(&pos2[v >> 16], 1);
            colsrc[bstart + p] = (ushort_t)(v & 0xFFFF);
        }
    }
    if (b == NBKT - 1 && t == 0) rowstart[NN] = E;
}

// ---------------- per-layer: node -> (q_s, q_d) in fp16 ----------------
__global__ __launch_bounds__(256) void k_q(
    const float* __restrict__ pin, int pstride, int c0, int c1, int c2,
    const float* __restrict__ W1l, const float* __restrict__ b1l,
    const float* __restrict__ scale, const float* __restrict__ shift, int use_bn,
    __half* __restrict__ qs, __half* __restrict__ qd) {
    int idx = blockIdx.x * 256 + threadIdx.x;   // v*64 + c
    int v = idx >> 6, c = idx & 63;
    const float* prow = pin + (size_t)v * pstride;
    float p0 = prow[c0], p1 = prow[c1], p2 = prow[c2];
    if (use_bn) {
        p0 = fmaxf(0.f, p0 * scale[0] + shift[0]);
        p1 = fmaxf(0.f, p1 * scale[1] + shift[1]);
        p2 = fmaxf(0.f, p2 * scale[2] + shift[2]);
    }
    float w0 = W1l[0 * 64 + c], w1 = W1l[1 * 64 + c], w2 = W1l[2 * 64 + c];
    float w3 = W1l[3 * 64 + c], w4 = W1l[4 * 64 + c], w5 = W1l[5 * 64 + c];
    qs[idx] = __float2half(p0 * w0 + p1 * w1 + p2 * w2);
    qd[idx] = __float2half(p0 * (w3 - w0) + p1 * (w4 - w1) + p2 * (w5 - w2) + b1l[c]);
}

// ---------------- vectorized edge accumulation ----------------
// lane L: edge-slot es=L>>3, channel-group cg=L&7 (channels cg*8 .. cg*8+7)
// one dwordx4 load = 8 halves; 8 edges/instr/wave; fp16 pk-accumulate per
// 64-edge chunk, dump to fp32 at chunk end (bounds fp16 error to ~9 terms).
__device__ __forceinline__ half2v bitcast_h2(unsigned int u) {
    union { unsigned int u; half2v h; } cvt;
    cvt.u = u;
    return cvt.h;
}

// fp32-accum variant (self loop only)
__device__ __forceinline__ void accum8f(const char* __restrict__ qsb, unsigned int byteoff,
                                        const half2v qd2[4], float acc[8]) {
    uint4 q = *reinterpret_cast<const uint4*>(qsb + byteoff);
    unsigned int wd[4] = {q.x, q.y, q.z, q.w};
    const half2v z2 = {(_Float16)0.0f, (_Float16)0.0f};
#pragma unroll
    for (int d = 0; d < 4; ++d) {
        half2v r = bitcast_h2(wd[d]) + qd2[d];
        r = __builtin_elementwise_max(r, z2);
        acc[2 * d]     += (float)r.x;
        acc[2 * d + 1] += (float)r.y;
    }
}

// edge loop: fills acc[8] (per-lane partial sums, to be butterflied over es)
__device__ __forceinline__ void edge_loop(const char* __restrict__ qsb,
                                          const ushort_t* __restrict__ colsrc,
                                          int start, int end, int es, int cg,
                                          const half2v qd2[4], float acc[8]) {
    int lane = (es << 3) | cg;
    unsigned int cg16 = (unsigned int)(cg << 4);
    const half2v z2 = {(_Float16)0.0f, (_Float16)0.0f};
    int i = start;
    while (i < end) {
        int cnt = min(64, end - i);
        int sl = (lane < cnt) ? (int)colsrc[i + lane] : 0;
        half2v h[4] = {z2, z2, z2, z2};
        int nfull = cnt & ~7;
        int j = 0;
        for (; j < nfull; j += 8) {
            int s = __shfl(sl, j + es);
            uint4 q = *reinterpret_cast<const uint4*>(qsb + (((unsigned int)(s << 7)) | cg16));
            unsigned int wd[4] = {q.x, q.y, q.z, q.w};
#pragma unroll
            for (int d = 0; d < 4; ++d) {
                half2v r = bitcast_h2(wd[d]) + qd2[d];      // v_pk_add_f16
                r = __builtin_elementwise_max(r, z2);       // v_pk_max_f16
                h[d] += r;                                  // v_pk_add_f16
            }
        }
        if (j < cnt) {
            int slot = j + es;
            int s = __shfl(sl, slot);
            bool ok = slot < cnt;
            uint4 q = *reinterpret_cast<const uint4*>(qsb + (((unsigned int)(s << 7)) | cg16));
            unsigned int wd[4] = {q.x, q.y, q.z, q.w};
#pragma unroll
            for (int d = 0; d < 4; ++d) {
                half2v r = bitcast_h2(wd[d]) + qd2[d];
                r = __builtin_elementwise_max(r, z2);
                if (ok) h[d] += r;
            }
        }
#pragma unroll
        for (int d = 0; d < 4; ++d) {
            acc[2 * d]     += (float)h[d].x;
            acc[2 * d + 1] += (float)h[d].y;
        }
        i += cnt;
    }
}

// ---------------- gather + reduce, layers 0..4 (3 output cols) ----------------
__global__ __launch_bounds__(256) void k_gather3(
    const __half* __restrict__ qs, const __half* __restrict__ qd,
    const int* __restrict__ rowstart, const ushort_t* __restrict__ colsrc,
    const float* __restrict__ W2l, const float* __restrict__ b2l,
    float* __restrict__ pnext, float* __restrict__ partials) {
    __shared__ float w2c[3][64];
    __shared__ float b2c[3];
    __shared__ float part[4][8];
    int tid = threadIdx.x;
    if (tid < 192) {
        int cj = tid >> 6;
        int col = (cj == 0) ? 0 : ((cj == 1) ? 1 : 14);
        w2c[cj][tid & 63] = W2l[(tid & 63) * 64 + col];
    }
    if (tid < 3) b2c[tid] = b2l[(tid == 0) ? 0 : ((tid == 1) ? 1 : 14)];
    __syncthreads();

    int w = tid >> 6, lane = tid & 63;
    int es = lane >> 3, cg = lane & 7;
    int v = blockIdx.x * 4 + w;
    const char* qsb = (const char*)qs;
    uint4 qq = ((const uint4*)qd)[(size_t)v * 8 + cg];
    unsigned int qw[4] = {qq.x, qq.y, qq.z, qq.w};
    half2v qd2[4];
#pragma unroll
    for (int d = 0; d < 4; ++d) qd2[d] = bitcast_h2(qw[d]);

    float acc[8] = {0, 0, 0, 0, 0, 0, 0, 0};
    int start = rowstart[v], end = rowstart[v + 1];
    if (es == 0) accum8f(qsb, ((unsigned int)(v << 7)) | (cg << 4), qd2, acc);  // self loop
    edge_loop(qsb, colsrc, start, end, es, cg, qd2, acc);

    // fold the 8 edge-slots
#pragma unroll
    for (int k = 0; k < 8; ++k) {
        acc[k] += __shfl_xor(acc[k], 8);
        acc[k] += __shfl_xor(acc[k], 16);
        acc[k] += __shfl_xor(acc[k], 32);
    }
    float degp1 = (float)(end - start + 1);
#pragma unroll
    for (int j = 0; j < 3; ++j) {
        float t = 0.f;
#pragma unroll
        for (int k = 0; k < 8; ++k) t += acc[k] * w2c[j][cg * 8 + k];
        t += __shfl_xor(t, 1);
        t += __shfl_xor(t, 2);
        t += __shfl_xor(t, 4);
        if (lane == 0) {
            float val = t + degp1 * b2c[j];
            pnext[v * 3 + j] = val;
            part[w][j] = val;
            part[w][3 + j] = val * val;
        }
    }
    __syncthreads();
    if (tid < 6) {
        float ssum = part[0][tid] + part[1][tid] + part[2][tid] + part[3][tid];
        partials[blockIdx.x * 8 + tid] = ssum;
    }
}

// ---------------- BN finalize (3 cols): partials -> scale/shift ----------------
__global__ void k_bnfin(const float* __restrict__ partials, int nb,
                        const float* __restrict__ gamma_l, const float* __restrict__ beta_l,
                        float* __restrict__ scale, float* __restrict__ shift) {
    __shared__ float lds[256][6];
    int t = threadIdx.x;
    float s[6] = {0, 0, 0, 0, 0, 0};
    for (int b = t; b < nb; b += 256)
        for (int j = 0; j < 6; ++j) s[j] += partials[b * 8 + j];
    for (int j = 0; j < 6; ++j) lds[t][j] = s[j];
    __syncthreads();
    for (int off = 128; off; off >>= 1) {
        if (t < off)
            for (int j = 0; j < 6; ++j) lds[t][j] += lds[t + off][j];
        __syncthreads();
    }
    if (t < 3) {
        const int cols[3] = {0, 1, 14};
        float mu = lds[0][t] / (float)NN;
        float var = lds[0][t + 3] / (float)NN - mu * mu;
        float rs = rsqrtf(var + EPSV);
        float g = gamma_l[cols[t]];
        scale[t] = rs * g;
        shift[t] = beta_l[cols[t]] - mu * rs * g;
    }
}

// ---------------- gather + full 64-col matmul, layer 5 ----------------
__global__ __launch_bounds__(256) void k_gather_full(
    const __half* __restrict__ qs, const __half* __restrict__ qd,
    const int* __restrict__ rowstart, const ushort_t* __restrict__ colsrc,
    const float* __restrict__ W2l, const float* __restrict__ b2l,
    float* __restrict__ out) {
    __shared__ float lds[4][64];
    int tid = threadIdx.x;
    int w = tid >> 6, lane = tid & 63;
    int es = lane >> 3, cg = lane & 7;
    int v = blockIdx.x * 4 + w;
    const char* qsb = (const char*)qs;
    uint4 qq = ((const uint4*)qd)[(size_t)v * 8 + cg];
    unsigned int qw[4] = {qq.x, qq.y, qq.z, qq.w};
    half2v qd2[4];
#pragma unroll
    for (int d = 0; d < 4; ++d) qd2[d] = bitcast_h2(qw[d]);

    float acc[8] = {0, 0, 0, 0, 0, 0, 0, 0};
    int start = rowstart[v], end = rowstart[v + 1];
    if (es == 0) accum8f(qsb, ((unsigned int)(v << 7)) | (cg << 4), qd2, acc);  // self loop
    edge_loop(qsb, colsrc, start, end, es, cg, qd2, acc);

#pragma unroll
    for (int k = 0; k < 8; ++k) {
        acc[k] += __shfl_xor(acc[k], 8);
        acc[k] += __shfl_xor(acc[k], 16);
        acc[k] += __shfl_xor(acc[k], 32);
    }
    if (es == 0) {
#pragma unroll
        for (int k = 0; k < 8; ++k) lds[w][cg * 8 + k] = acc[k];
    }
    __syncthreads();
    float degp1 = (float)(end - start + 1);
    float sum = degp1 * b2l[lane];
    for (int k = 0; k < 64; ++k) sum += lds[w][k] * W2l[k * 64 + lane];
    out[v * 64 + lane] = sum;
}

// ---------------- launch ----------------

static inline size_t align_up(size_t x) { return (x + 255) & ~(size_t)255; }

extern "C" void kernel_launch(void* const* d_in, const int* in_sizes, int n_in,
                              void* d_out, int out_size, void* d_ws, size_t ws_size,
                              hipStream_t stream) {
    const float* x     = (const float*)d_in[0];
    const int*   ei    = (const int*)d_in[1];
    const float* W1    = (const float*)d_in[2];
    const float* b1    = (const float*)d_in[3];
    const float* W2    = (const float*)d_in[4];
    const float* b2    = (const float*)d_in[5];
    const float* gamma = (const float*)d_in[6];
    const float* beta  = (const float*)d_in[7];
    float* out = (float*)d_out;
    const int E = in_sizes[1] / 2;           // 1,600,000
    const int* src = ei;
    const int* dst = ei + E;

    const int nchunk = (E + CHUNK - 1) / CHUNK;     // 391
    const int nscan  = NBKT * nchunk;               // ~152,881
    const int nsb    = (nscan + 255) / 256;         // ~598

    // workspace carve
    char* base = (char*)d_ws;
    size_t off = 0;
    __half* qs = (__half*)(base + off);     off = align_up(off + (size_t)NN * 64 * 2);
    __half* qd = (__half*)(base + off);     off = align_up(off + (size_t)NN * 64 * 2);
    float* pA = (float*)(base + off);       off = align_up(off + (size_t)NN * 3 * 4);
    float* pB = (float*)(base + off);       off = align_up(off + (size_t)NN * 3 * 4);
    int* rowstart = (int*)(base + off);     off = align_up(off + (size_t)(NN + 1) * 4);
    ushort_t* colsrc = (ushort_t*)(base + off); off = align_up(off + (size_t)E * 2);
    int* ebuf     = (int*)(base + off);     off = align_up(off + (size_t)E * 4);
    int* hist     = (int*)(base + off);     off = align_up(off + (size_t)nscan * 4);
    int* offsT    = (int*)(base + off);     off = align_up(off + (size_t)nscan * 4);
    int* presum   = (int*)(base + off);     off = align_up(off + (size_t)nscan * 4);
    int* bsum     = (int*)(base + off);     off = align_up(off + (size_t)nsb * 4);
    int* boff     = (int*)(base + off);     off = align_up(off + (size_t)nsb * 4);
    float* partials = (float*)(base + off); off = align_up(off + (size_t)NBLK * 8 * 4);
    float* scale = (float*)(base + off);    off = align_up(off + 64 * 4);
    float* shift = (float*)(base + off);    off = align_up(off + 64 * 4);
    (void)ws_size; (void)n_in; (void)out_size;

    // CSR build: two-stage counting sort, no global atomics
    k_hist1<<<nchunk, 256, 0, stream>>>(dst, E, nchunk, hist);
    k_scanA<<<nsb, 256, 0, stream>>>(hist, nscan, presum, bsum);
    k_scanB<<<1, 256, 0, stream>>>(bsum, nsb, boff);
    k_scanC<<<nsb, 256, 0, stream>>>(presum, hist, boff, nscan, nchunk, offsT);
    k_scatter1<<<nchunk, 256, 0, stream>>>(src, dst, E, offsT, ebuf);
    k_bucket_csr<<<NBKT, 256, 0, stream>>>(ebuf, offsT, E, rowstart, colsrc);

    float* pc = pA;
    float* pn = pB;
    for (int l = 0; l < 6; ++l) {
        const float* pin = (l == 0) ? x : pc;
        int pstride = (l == 0) ? 16 : 3;
        int c0 = 0, c1 = 1, c2 = (l == 0) ? 14 : 2;
        k_q<<<NBLK, 256, 0, stream>>>(pin, pstride, c0, c1, c2,
                                      W1 + (size_t)l * 6 * 64, b1 + (size_t)l * 64,
                                      scale, shift, (l > 0) ? 1 : 0, qs, qd);
        if (l < 5) {
            k_gather3<<<NBLK, 256, 0, stream>>>(qs, qd, rowstart, colsrc,
                                                W2 + (size_t)l * 64 * 64, b2 + (size_t)l * 64,
                                                pn, partials);
            k_bnfin<<<1, 256, 0, stream>>>(partials, NBLK,
                                           gamma + (size_t)l * 64, beta + (size_t)l * 64,
                                           scale, shift);
            float* tmp = pc; pc = pn; pn = tmp;
        } else {
            k_gather_full<<<NBLK, 256, 0, stream>>>(qs, qd, rowstart, colsrc,
                                                    W2 + (size_t)5 * 64 * 64, b2 + (size_t)5 * 64,
                                                    out);
        }
    }
}

// Round 7
// 517.551 us; speedup vs baseline: 2.2842x; 1.0169x over previous
//
#include <hip/hip_runtime.h>
#include <hip/hip_fp16.h>
#include <cstdint>

#define NN 50000
#define NBLK 12500              // NN/4 nodes per 256-thread block (4 waves)
#define EPSV 1e-5f

// bucket sort params
#define NPB 128                 // nodes per bucket
#define BSH 7                   // log2(NPB)
#define NBKT 391                // ceil(NN/NPB)
#define CHUNK 4096              // edges per stage-1 block
#define EPT 16                  // edges per thread (CHUNK/256)
#define LDSE 6144               // per-bucket LDS edge capacity (mean ~4096, 32 sigma)

typedef unsigned short ushort_t;
typedef _Float16 half2v __attribute__((ext_vector_type(2)));

// ---------------- stage 1: per-chunk bucket histogram ----------------
__global__ __launch_bounds__(256) void k_hist1(const int* __restrict__ dst, int E, int nchunk,
                                               int* __restrict__ hist) {
    __shared__ int cnt[NBKT];
    int t = threadIdx.x, blk = blockIdx.x;
    for (int b = t; b < NBKT; b += 256) cnt[b] = 0;
    __syncthreads();
    int base = blk * CHUNK;
#pragma unroll
    for (int k = 0; k < EPT; ++k) {
        int e = base + k * 256 + t;
        if (e < E) atomicAdd(&cnt[dst[e] >> BSH], 1);
    }
    __syncthreads();
    for (int b = t; b < NBKT; b += 256) hist[(size_t)b * nchunk + blk] = cnt[b];
}

// ---------------- generic hierarchical exclusive scan ----------------
__global__ __launch_bounds__(256) void k_scanA(const int* __restrict__ in, int n,
                                               int* __restrict__ presum, int* __restrict__ blocksum) {
    __shared__ int lds[256];
    int t = threadIdx.x, g = blockIdx.x * 256 + t;
    int v = (g < n) ? in[g] : 0;
    lds[t] = v;
    __syncthreads();
    for (int off = 1; off < 256; off <<= 1) {
        int x = (t >= off) ? lds[t - off] : 0;
        __syncthreads();
        lds[t] += x;
        __syncthreads();
    }
    if (g < n) presum[g] = lds[t];               // block-local inclusive
    if (t == 255) blocksum[blockIdx.x] = lds[255];
}

// single-block loop-carried exclusive scan of nb block sums
__global__ __launch_bounds__(256) void k_scanB(const int* __restrict__ blocksum,
                                               int nb, int* __restrict__ blockoff) {
    __shared__ int lds[256];
    __shared__ int carry_s;
    int t = threadIdx.x;
    if (t == 0) carry_s = 0;
    __syncthreads();
    for (int base = 0; base < nb; base += 256) {
        int g = base + t;
        int v = (g < nb) ? blocksum[g] : 0;
        lds[t] = v;
        __syncthreads();
        for (int off = 1; off < 256; off <<= 1) {
            int x = (t >= off) ? lds[t - off] : 0;
            __syncthreads();
            lds[t] += x;
            __syncthreads();
        }
        if (g < nb) blockoff[g] = lds[t] - v + carry_s;
        __syncthreads();
        if (t == 255) carry_s += lds[255];
        __syncthreads();
    }
}

// combine -> transposed offsets: offsT[c*NBKT + b] (chunk-major, coalesced for scatter)
__global__ __launch_bounds__(256) void k_scanC(const int* __restrict__ presum,
                                               const int* __restrict__ hist,
                                               const int* __restrict__ blockoff,
                                               int n, int nchunk, int* __restrict__ offsT) {
    int g = blockIdx.x * 256 + threadIdx.x;
    if (g < n) {
        int val = presum[g] - hist[g] + blockoff[blockIdx.x];
        int b = g / nchunk;
        int c = g - b * nchunk;
        offsT[(size_t)c * NBKT + b] = val;
    }
}

// ---------------- stage 1: partition edges into buckets ----------------
// pack = (local_dst << 16) | src   (src < 65536, local_dst < 128)
__global__ __launch_bounds__(256) void k_scatter1(const int* __restrict__ src,
                                                  const int* __restrict__ dst, int E,
                                                  const int* __restrict__ offsT,
                                                  int* __restrict__ ebuf) {
    __shared__ int pos[NBKT];
    int t = threadIdx.x, blk = blockIdx.x;
    for (int b = t; b < NBKT; b += 256) pos[b] = offsT[(size_t)blk * NBKT + b];
    __syncthreads();
    int base = blk * CHUNK;
#pragma unroll
    for (int k = 0; k < EPT; ++k) {
        int e = base + k * 256 + t;
        if (e < E) {
            int d = dst[e];
            int b = d >> BSH;
            int p = atomicAdd(&pos[b], 1);
            ebuf[p] = ((d & (NPB - 1)) << 16) | src[e];
        }
    }
}

// ---------------- stage 2: per-bucket CSR (coalesced writes, ushort colsrc) ----------------
__global__ __launch_bounds__(256) void k_bucket_csr(const int* __restrict__ ebuf,
                                                    const int* __restrict__ offsT, int E,
                                                    int* __restrict__ rowstart,
                                                    ushort_t* __restrict__ colsrc) {
    __shared__ int cnt[NPB];
    __shared__ int s[NPB];
    __shared__ int pos2[NPB];
    __shared__ ushort_t lout[LDSE];
    int t = threadIdx.x, b = blockIdx.x;
    int bstart = offsT[b];
    int bend = (b + 1 < NBKT) ? offsT[b + 1] : E;
    int m = bend - bstart;
    if (t < NPB) cnt[t] = 0;
    __syncthreads();
    for (int i = bstart + t; i < bend; i += 256) atomicAdd(&cnt[ebuf[i] >> 16], 1);
    __syncthreads();
    if (t < NPB) s[t] = cnt[t];
    __syncthreads();
    for (int off = 1; off < NPB; off <<= 1) {
        int x = (t < NPB && t >= off) ? s[t - off] : 0;
        __syncthreads();
        if (t < NPB) s[t] += x;
        __syncthreads();
    }
    if (t < NPB) {
        int excl = s[t] - cnt[t];
        int node = b * NPB + t;
        if (node < NN) rowstart[node] = bstart + excl;
        pos2[t] = excl;
    }
    __syncthreads();
    if (m <= LDSE) {
        for (int i = bstart + t; i < bend; i += 256) {
            int v = ebuf[i];
            int p = atomicAdd(&pos2[v >> 16], 1);
            lout[p] = (ushort_t)(v & 0xFFFF);
        }
        __syncthreads();
        for (int i = t; i < m; i += 256) colsrc[bstart + i] = lout[i];
    } else {
        // overflow fallback (statistically unreachable): direct global scatter
        for (int i = bstart + t; i < bend; i += 256) {
            int v = ebuf[i];
            int p = atomicAdd(&pos2[v >> 16], 1);
            colsrc[bstart + p] = (ushort_t)(v & 0xFFFF);
        }
    }
    if (b == NBKT - 1 && t == 0) rowstart[NN] = E;
}

// ---------------- per-layer: node -> (q_s, q_d) in fp16 ----------------
__global__ __launch_bounds__(256) void k_q(
    const float* __restrict__ pin, int pstride, int c0, int c1, int c2,
    const float* __restrict__ W1l, const float* __restrict__ b1l,
    const float* __restrict__ scale, const float* __restrict__ shift, int use_bn,
    __half* __restrict__ qs, __half* __restrict__ qd) {
    int idx = blockIdx.x * 256 + threadIdx.x;   // v*64 + c
    int v = idx >> 6, c = idx & 63;
    const float* prow = pin + (size_t)v * pstride;
    float p0 = prow[c0], p1 = prow[c1], p2 = prow[c2];
    if (use_bn) {
        p0 = fmaxf(0.f, p0 * scale[0] + shift[0]);
        p1 = fmaxf(0.f, p1 * scale[1] + shift[1]);
        p2 = fmaxf(0.f, p2 * scale[2] + shift[2]);
    }
    float w0 = W1l[0 * 64 + c], w1 = W1l[1 * 64 + c], w2 = W1l[2 * 64 + c];
    float w3 = W1l[3 * 64 + c], w4 = W1l[4 * 64 + c], w5 = W1l[5 * 64 + c];
    qs[idx] = __float2half(p0 * w0 + p1 * w1 + p2 * w2);
    qd[idx] = __float2half(p0 * (w3 - w0) + p1 * (w4 - w1) + p2 * (w5 - w2) + b1l[c]);
}

// ---------------- vectorized edge accumulation ----------------
// lane L: edge-slot es=L>>3, channel-group cg=L&7 (channels cg*8 .. cg*8+7)
// Fully unrolled 8-wide: all 8 dwordx4 loads issued before any consume
// (8 loads in flight per wave -> latency hiding). Masked slots have sl=0
// so they load row 0: one always-hot L2 line, no branch needed.
__device__ __forceinline__ half2v bitcast_h2(unsigned int u) {
    union { unsigned int u; half2v h; } cvt;
    cvt.u = u;
    return cvt.h;
}

// fp32-accum variant (self loop only)
__device__ __forceinline__ void accum8f(const char* __restrict__ qsb, unsigned int byteoff,
                                        const half2v qd2[4], float acc[8]) {
    uint4 q = *reinterpret_cast<const uint4*>(qsb + byteoff);
    unsigned int wd[4] = {q.x, q.y, q.z, q.w};
    const half2v z2 = {(_Float16)0.0f, (_Float16)0.0f};
#pragma unroll
    for (int d = 0; d < 4; ++d) {
        half2v r = bitcast_h2(wd[d]) + qd2[d];
        r = __builtin_elementwise_max(r, z2);
        acc[2 * d]     += (float)r.x;
        acc[2 * d + 1] += (float)r.y;
    }
}

// edge loop: fills acc[8] (per-lane partial sums, to be butterflied over es)
__device__ __forceinline__ void edge_loop(const char* __restrict__ qsb,
                                          const ushort_t* __restrict__ colsrc,
                                          int start, int end, int es, int cg,
                                          const half2v qd2[4], float acc[8]) {
    int lane = (es << 3) | cg;
    unsigned int cg16 = (unsigned int)(cg << 4);
    const half2v z2 = {(_Float16)0.0f, (_Float16)0.0f};
    int i = start;
    while (i < end) {
        int cnt = min(64, end - i);
        int sl = (lane < cnt) ? (int)colsrc[i + lane] : 0;
        // phase 1: issue all 8 gather loads (independent, 8 in flight)
        uint4 q[8];
#pragma unroll
        for (int k = 0; k < 8; ++k) {
            int s = __shfl(sl, (k << 3) + es);
            q[k] = *reinterpret_cast<const uint4*>(qsb + (((unsigned int)(s << 7)) | cg16));
        }
        // phase 2: consume with predicated pk math; fp16 chunk accumulator
        half2v h[4] = {z2, z2, z2, z2};
#pragma unroll
        for (int k = 0; k < 8; ++k) {
            bool ok = ((k << 3) + es) < cnt;
            unsigned int wd[4] = {q[k].x, q[k].y, q[k].z, q[k].w};
#pragma unroll
            for (int d = 0; d < 4; ++d) {
                half2v r = bitcast_h2(wd[d]) + qd2[d];      // v_pk_add_f16
                r = __builtin_elementwise_max(r, z2);       // v_pk_max_f16
                h[d] += ok ? r : z2;                        // cndmask + v_pk_add_f16
            }
        }
#pragma unroll
        for (int d = 0; d < 4; ++d) {
            acc[2 * d]     += (float)h[d].x;
            acc[2 * d + 1] += (float)h[d].y;
        }
        i += cnt;
    }
}

// ---------------- gather + reduce, layers 0..4 (3 output cols) ----------------
__global__ __launch_bounds__(256) void k_gather3(
    const __half* __restrict__ qs, const __half* __restrict__ qd,
    const int* __restrict__ rowstart, const ushort_t* __restrict__ colsrc,
    const float* __restrict__ W2l, const float* __restrict__ b2l,
    float* __restrict__ pnext, float* __restrict__ partials) {
    __shared__ float w2c[3][64];
    __shared__ float b2c[3];
    __shared__ float part[4][8];
    int tid = threadIdx.x;
    if (tid < 192) {
        int cj = tid >> 6;
        int col = (cj == 0) ? 0 : ((cj == 1) ? 1 : 14);
        w2c[cj][tid & 63] = W2l[(tid & 63) * 64 + col];
    }
    if (tid < 3) b2c[tid] = b2l[(tid == 0) ? 0 : ((tid == 1) ? 1 : 14)];
    __syncthreads();

    int w = tid >> 6, lane = tid & 63;
    int es = lane >> 3, cg = lane & 7;
    int v = blockIdx.x * 4 + w;
    const char* qsb = (const char*)qs;
    uint4 qq = ((const uint4*)qd)[(size_t)v * 8 + cg];
    unsigned int qw[4] = {qq.x, qq.y, qq.z, qq.w};
    half2v qd2[4];
#pragma unroll
    for (int d = 0; d < 4; ++d) qd2[d] = bitcast_h2(qw[d]);

    float acc[8] = {0, 0, 0, 0, 0, 0, 0, 0};
    int start = rowstart[v], end = rowstart[v + 1];
    if (es == 0) accum8f(qsb, ((unsigned int)(v << 7)) | (cg << 4), qd2, acc);  // self loop
    edge_loop(qsb, colsrc, start, end, es, cg, qd2, acc);

    // fold the 8 edge-slots
#pragma unroll
    for (int k = 0; k < 8; ++k) {
        acc[k] += __shfl_xor(acc[k], 8);
        acc[k] += __shfl_xor(acc[k], 16);
        acc[k] += __shfl_xor(acc[k], 32);
    }
    float degp1 = (float)(end - start + 1);
#pragma unroll
    for (int j = 0; j < 3; ++j) {
        float t = 0.f;
#pragma unroll
        for (int k = 0; k < 8; ++k) t += acc[k] * w2c[j][cg * 8 + k];
        t += __shfl_xor(t, 1);
        t += __shfl_xor(t, 2);
        t += __shfl_xor(t, 4);
        if (lane == 0) {
            float val = t + degp1 * b2c[j];
            pnext[v * 3 + j] = val;
            part[w][j] = val;
            part[w][3 + j] = val * val;
        }
    }
    __syncthreads();
    if (tid < 6) {
        float ssum = part[0][tid] + part[1][tid] + part[2][tid] + part[3][tid];
        partials[blockIdx.x * 8 + tid] = ssum;
    }
}

// ---------------- BN finalize (3 cols): partials -> scale/shift ----------------
__global__ void k_bnfin(const float* __restrict__ partials, int nb,
                        const float* __restrict__ gamma_l, const float* __restrict__ beta_l,
                        float* __restrict__ scale, float* __restrict__ shift) {
    __shared__ float lds[256][6];
    int t = threadIdx.x;
    float s[6] = {0, 0, 0, 0, 0, 0};
    for (int b = t; b < nb; b += 256)
        for (int j = 0; j < 6; ++j) s[j] += partials[b * 8 + j];
    for (int j = 0; j < 6; ++j) lds[t][j] = s[j];
    __syncthreads();
    for (int off = 128; off; off >>= 1) {
        if (t < off)
            for (int j = 0; j < 6; ++j) lds[t][j] += lds[t + off][j];
        __syncthreads();
    }
    if (t < 3) {
        const int cols[3] = {0, 1, 14};
        float mu = lds[0][t] / (float)NN;
        float var = lds[0][t + 3] / (float)NN - mu * mu;
        float rs = rsqrtf(var + EPSV);
        float g = gamma_l[cols[t]];
        scale[t] = rs * g;
        shift[t] = beta_l[cols[t]] - mu * rs * g;
    }
}

// ---------------- gather + full 64-col matmul, layer 5 ----------------
__global__ __launch_bounds__(256) void k_gather_full(
    const __half* __restrict__ qs, const __half* __restrict__ qd,
    const int* __restrict__ rowstart, const ushort_t* __restrict__ colsrc,
    const float* __restrict__ W2l, const float* __restrict__ b2l,
    float* __restrict__ out) {
    __shared__ float lds[4][64];
    int tid = threadIdx.x;
    int w = tid >> 6, lane = tid & 63;
    int es = lane >> 3, cg = lane & 7;
    int v = blockIdx.x * 4 + w;
    const char* qsb = (const char*)qs;
    uint4 qq = ((const uint4*)qd)[(size_t)v * 8 + cg];
    unsigned int qw[4] = {qq.x, qq.y, qq.z, qq.w};
    half2v qd2[4];
#pragma unroll
    for (int d = 0; d < 4; ++d) qd2[d] = bitcast_h2(qw[d]);

    float acc[8] = {0, 0, 0, 0, 0, 0, 0, 0};
    int start = rowstart[v], end = rowstart[v + 1];
    if (es == 0) accum8f(qsb, ((unsigned int)(v << 7)) | (cg << 4), qd2, acc);  // self loop
    edge_loop(qsb, colsrc, start, end, es, cg, qd2, acc);

#pragma unroll
    for (int k = 0; k < 8; ++k) {
        acc[k] += __shfl_xor(acc[k], 8);
        acc[k] += __shfl_xor(acc[k], 16);
        acc[k] += __shfl_xor(acc[k], 32);
    }
    if (es == 0) {
#pragma unroll
        for (int k = 0; k < 8; ++k) lds[w][cg * 8 + k] = acc[k];
    }
    __syncthreads();
    float degp1 = (float)(end - start + 1);
    float sum = degp1 * b2l[lane];
    for (int k = 0; k < 64; ++k) sum += lds[w][k] * W2l[k * 64 + lane];
    out[v * 64 + lane] = sum;
}

// ---------------- launch ----------------

static inline size_t align_up(size_t x) { return (x + 255) & ~(size_t)255; }

extern "C" void kernel_launch(void* const* d_in, const int* in_sizes, int n_in,
                              void* d_out, int out_size, void* d_ws, size_t ws_size,
                              hipStream_t stream) {
    const float* x     = (const float*)d_in[0];
    const int*   ei    = (const int*)d_in[1];
    const float* W1    = (const float*)d_in[2];
    const float* b1    = (const float*)d_in[3];
    const float* W2    = (const float*)d_in[4];
    const float* b2    = (const float*)d_in[5];
    const float* gamma = (const float*)d_in[6];
    const float* beta  = (const float*)d_in[7];
    float* out = (float*)d_out;
    const int E = in_sizes[1] / 2;           // 1,600,000
    const int* src = ei;
    const int* dst = ei + E;

    const int nchunk = (E + CHUNK - 1) / CHUNK;     // 391
    const int nscan  = NBKT * nchunk;               // ~152,881
    const int nsb    = (nscan + 255) / 256;         // ~598

    // workspace carve
    char* base = (char*)d_ws;
    size_t off = 0;
    __half* qs = (__half*)(base + off);     off = align_up(off + (size_t)NN * 64 * 2);
    __half* qd = (__half*)(base + off);     off = align_up(off + (size_t)NN * 64 * 2);
    float* pA = (float*)(base + off);       off = align_up(off + (size_t)NN * 3 * 4);
    float* pB = (float*)(base + off);       off = align_up(off + (size_t)NN * 3 * 4);
    int* rowstart = (int*)(base + off);     off = align_up(off + (size_t)(NN + 1) * 4);
    ushort_t* colsrc = (ushort_t*)(base + off); off = align_up(off + (size_t)E * 2);
    int* ebuf     = (int*)(base + off);     off = align_up(off + (size_t)E * 4);
    int* hist     = (int*)(base + off);     off = align_up(off + (size_t)nscan * 4);
    int* offsT    = (int*)(base + off);     off = align_up(off + (size_t)nscan * 4);
    int* presum   = (int*)(base + off);     off = align_up(off + (size_t)nscan * 4);
    int* bsum     = (int*)(base + off);     off = align_up(off + (size_t)nsb * 4);
    int* boff     = (int*)(base + off);     off = align_up(off + (size_t)nsb * 4);
    float* partials = (float*)(base + off); off = align_up(off + (size_t)NBLK * 8 * 4);
    float* scale = (float*)(base + off);    off = align_up(off + 64 * 4);
    float* shift = (float*)(base + off);    off = align_up(off + 64 * 4);
    (void)ws_size; (void)n_in; (void)out_size;

    // CSR build: two-stage counting sort, no global atomics
    k_hist1<<<nchunk, 256, 0, stream>>>(dst, E, nchunk, hist);
    k_scanA<<<nsb, 256, 0, stream>>>(hist, nscan, presum, bsum);
    k_scanB<<<1, 256, 0, stream>>>(bsum, nsb, boff);
    k_scanC<<<nsb, 256, 0, stream>>>(presum, hist, boff, nscan, nchunk, offsT);
    k_scatter1<<<nchunk, 256, 0, stream>>>(src, dst, E, offsT, ebuf);
    k_bucket_csr<<<NBKT, 256, 0, stream>>>(ebuf, offsT, E, rowstart, colsrc);

    float* pc = pA;
    float* pn = pB;
    for (int l = 0; l < 6; ++l) {
        const float* pin = (l == 0) ? x : pc;
        int pstride = (l == 0) ? 16 : 3;
        int c0 = 0, c1 = 1, c2 = (l == 0) ? 14 : 2;
        k_q<<<NBLK, 256, 0, stream>>>(pin, pstride, c0, c1, c2,
                                      W1 + (size_t)l * 6 * 64, b1 + (size_t)l * 64,
                                      scale, shift, (l > 0) ? 1 : 0, qs, qd);
        if (l < 5) {
            k_gather3<<<NBLK, 256, 0, stream>>>(qs, qd, rowstart, colsrc,
                                                W2 + (size_t)l * 64 * 64, b2 + (size_t)l * 64,
                                                pn, partials);
            k_bnfin<<<1, 256, 0, stream>>>(partials, NBLK,
                                           gamma + (size_t)l * 64, beta + (size_t)l * 64,
                                           scale, shift);
            float* tmp = pc; pc = pn; pn = tmp;
        } else {
            k_gather_full<<<NBLK, 256, 0, stream>>>(qs, qd, rowstart, colsrc,
                                                    W2 + (size_t)5 * 64 * 64, b2 + (size_t)5 * 64,
                                                    out);
        }
    }
}